// Round 9
// baseline (773.946 us; speedup 1.0000x reference)
//
#include <hip/hip_runtime.h>

typedef unsigned short u16;
typedef __attribute__((ext_vector_type(4))) float f32x4;
typedef __attribute__((ext_vector_type(8))) short short8;
typedef __attribute__((ext_vector_type(4))) short short4v;

constexpr int CL  = 2;
constexpr int CH  = 2048;
constexpr int CNH = 16;
constexpr int CHD = 128;
constexpr int CFF = 4096;
constexpr int CS  = 1024;
constexpr int CB  = 2;
constexpr int CNL = 4;
constexpr int CM  = CB * CS;   // 2048 rows (B*S)
#define SCALING 8.0f

__device__ __constant__ float NF4TAB[16] = {
    -1.0f, -0.6961928009986877f, -0.5250730514526367f, -0.39491748809814453f,
    -0.28444138169288635f, -0.18477343022823334f, -0.09105003625154495f, 0.0f,
    0.07958029955625534f, 0.16093020141124725f, 0.24611230194568634f,
    0.33791524171829224f, 0.44070982933044434f, 0.5626170039176941f,
    0.7229568362236023f, 1.0f};

__device__ __forceinline__ u16 f2bf(float f) {
  union { float f; unsigned u; } v; v.f = f;
  unsigned r = v.u + 0x7fffu + ((v.u >> 16) & 1u);
  return (u16)(r >> 16);
}
__device__ __forceinline__ float bf2f(u16 u) {
  union { unsigned u; float f; } v; v.u = ((unsigned)u) << 16;
  return v.f;
}

template <int N> __device__ __forceinline__ void wait_vm() {
  if constexpr (N == 0)      asm volatile("s_waitcnt vmcnt(0)" ::: "memory");
  else if constexpr (N == 6) asm volatile("s_waitcnt vmcnt(6)" ::: "memory");
  else if constexpr (N == 8) asm volatile("s_waitcnt vmcnt(8)" ::: "memory");
  else                       asm volatile("s_waitcnt vmcnt(0)" ::: "memory");
}

__device__ __forceinline__ float blockReduceSum(float v) {
  __shared__ float sh[4];
  #pragma unroll
  for (int o = 32; o > 0; o >>= 1) v += __shfl_down(v, o);
  __syncthreads();
  if ((threadIdx.x & 63) == 0) sh[threadIdx.x >> 6] = v;
  __syncthreads();
  return sh[0] + sh[1] + sh[2] + sh[3];
}

// ---------------- embed gather
__global__ void k_embed(const int* __restrict__ ids, const float* __restrict__ emb,
                        float* __restrict__ x) {
  int m = blockIdx.x;
  const float4* src = (const float4*)(emb + (size_t)ids[m] * CH);
  float4* dst = (float4*)(x + (size_t)m * CH);
  for (int i = threadIdx.x; i < CH / 4; i += 256) dst[i] = src[i];
}

// ---------------- fused layernorm -> bf16  +  LoRA xA (R=2)
__global__ void k_ln_xa(const float* __restrict__ x, const float* __restrict__ g,
                        const float* __restrict__ b, const float* __restrict__ A,
                        u16* __restrict__ o, float* __restrict__ xA) {
  int m = blockIdx.x, tid = threadIdx.x;
  const float* row = x + (size_t)m * CH;
  float s = 0.f, s2 = 0.f;
  for (int i = tid; i < CH / 4; i += 256) {
    float4 v = ((const float4*)row)[i];
    s += v.x + v.y + v.z + v.w;
    s2 += v.x * v.x + v.y * v.y + v.z * v.z + v.w * v.w;
  }
  s = blockReduceSum(s);
  s2 = blockReduceSum(s2);
  float mu = s / CH, var = s2 / CH - mu * mu;
  float rs = rsqrtf(var + 1e-5f);
  u16* orow = o + (size_t)m * CH;
  float s0 = 0.f, s1 = 0.f;
  for (int i = tid; i < CH / 4; i += 256) {
    float4 v = ((const float4*)row)[i];
    float4 gv = ((const float4*)g)[i];
    float4 bv = ((const float4*)b)[i];
    float4 a0 = ((const float4*)A)[i];
    float4 a1 = ((const float4*)(A + CH))[i];
    float h0 = (v.x - mu) * rs * gv.x + bv.x;
    float h1 = (v.y - mu) * rs * gv.y + bv.y;
    float h2 = (v.z - mu) * rs * gv.z + bv.z;
    float h3 = (v.w - mu) * rs * gv.w + bv.w;
    short4v ov = { (short)f2bf(h0), (short)f2bf(h1), (short)f2bf(h2), (short)f2bf(h3) };
    *(short4v*)(orow + i * 4) = ov;
    s0 += h0 * a0.x + h1 * a0.y + h2 * a0.z + h3 * a0.w;
    s1 += h0 * a1.x + h1 * a1.y + h2 * a1.z + h3 * a1.w;
  }
  s0 = blockReduceSum(s0);
  s1 = blockReduceSum(s1);
  if (tid == 0) { xA[2 * m] = s0; xA[2 * m + 1] = s1; }
}

// ---------------- LoRA xA only (bf16 input)
__global__ void k_xa(const u16* __restrict__ xb, const float* __restrict__ A,
                     float* __restrict__ xA, int K) {
  int m = blockIdx.x, tid = threadIdx.x;
  const u16* row = xb + (size_t)m * K;
  float s0 = 0.f, s1 = 0.f;
  for (int c = tid; c < K / 8; c += 256) {
    short8 v = *(const short8*)(row + c * 8);
    #pragma unroll
    for (int e = 0; e < 8; ++e) {
      float f = bf2f((u16)v[e]);
      s0 += f * A[c * 8 + e];
      s1 += f * A[K + c * 8 + e];
    }
  }
  s0 = blockReduceSum(s0);
  s1 = blockReduceSum(s1);
  if (tid == 0) { xA[2 * m] = s0; xA[2 * m + 1] = s1; }
}

// ---------------- NF4 dequant -> bf16 row-major (N x K)
__global__ void k_dequant(const int* __restrict__ codes, const float* __restrict__ scales,
                          u16* __restrict__ w, int kshift, long total) {
  __shared__ float lut[16];
  if (threadIdx.x < 16) lut[threadIdx.x] = NF4TAB[threadIdx.x];
  __syncthreads();
  long base = ((long)blockIdx.x * 256 + threadIdx.x) * 8;
  if (base >= total) return;
  long n = base >> kshift;
  int k = (int)(base & ((1L << kshift) - 1));
  float sc = scales[(size_t)n * (1 << (kshift - 6)) + (k >> 6)];
  const int* cp = codes + base;
  short8 o;
  #pragma unroll
  for (int i = 0; i < 8; ++i) o[i] = (short)f2bf(lut[cp[i] & 15] * sc);
  *(short8*)(w + base) = o;
}

// ---------------- rope tables
__global__ void k_ropetab(float* __restrict__ cosT, float* __restrict__ sinT) {
  int i = blockIdx.x * 256 + threadIdx.x;
  if (i >= CS * 64) return;
  int s = i >> 6, d = i & 63;
  float inv = powf(10000.0f, -(float)d / 64.0f);
  float a = (float)s * inv;
  cosT[i] = cosf(a);
  sinT[i] = sinf(a);
}

// ---------------- rope + extract q,k -> (B,NH,S,HD) bf16  (bf16 input)
__global__ void k_rope(const u16* __restrict__ qkv, const float* __restrict__ cosT,
                       const float* __restrict__ sinT, u16* __restrict__ Qb,
                       u16* __restrict__ Kb) {
  int bid = blockIdx.x;            // z*CS + s
  int s = bid & (CS - 1);
  int z = bid >> 10;               // b*NH + h
  int b = z >> 4, h = z & 15;
  int d = threadIdx.x;             // 0..127
  const u16* base = qkv + ((size_t)(b * CS + s)) * (3 * CH) + h * (3 * CHD);
  int dh = d & 63;
  float c = cosT[s * 64 + dh], sn = sinT[s * 64 + dh];
  float sgn = (d < 64) ? -1.0f : 1.0f;
  float q = bf2f(base[d]),       qp = bf2f(base[d ^ 64]);
  float k = bf2f(base[CHD + d]), kp = bf2f(base[CHD + (d ^ 64)]);
  size_t oi = ((size_t)z * CS + s) * CHD + d;
  Qb[oi] = f2bf(q * c + sgn * qp * sn);
  Kb[oi] = f2bf(k * c + sgn * kp * sn);
}

// ---------------- V transpose -> (B,NH,HD,S) bf16  (bf16 input)
__global__ void k_vtrans(const u16* __restrict__ qkv, u16* __restrict__ Vt) {
  __shared__ u16 tile[32][33];
  int z = blockIdx.z;
  int b = z >> 4, h = z & 15;
  int s0 = blockIdx.x * 32, d0 = blockIdx.y * 32;
  int tx = threadIdx.x, ty = threadIdx.y;  // 32 x 8
  #pragma unroll
  for (int i = 0; i < 32; i += 8)
    tile[ty + i][tx] =
        qkv[((size_t)(b * CS + s0 + ty + i)) * (3 * CH) + h * (3 * CHD) + 2 * CHD + d0 + tx];
  __syncthreads();
  #pragma unroll
  for (int i = 0; i < 32; i += 8)
    Vt[((size_t)z * CHD + d0 + ty + i) * CS + s0 + tx] = tile[tx][ty + i];
}

// ---------------- flash attention (R4 champion structure; +3 blocks/CU, +setprio)
__global__ __launch_bounds__(256, 3) void k_flash(
    const u16* __restrict__ Qb, const u16* __restrict__ Kb, const u16* __restrict__ Vt,
    const int* __restrict__ amask, u16* __restrict__ out) {
  __shared__ u16 Ks[64 * 128];
  __shared__ u16 Vs[128 * 64];
  __shared__ float bias[CS];
  __shared__ u16 Ps[4][16][80];
  int bid = blockIdx.x;
  int qt = 15 - (bid >> 5);
  int z = bid & 31;
  int b = z >> 4, h = z & 15;
  int tid = threadIdx.x, lane = tid & 63, wid = tid >> 6;
  int lrow = lane & 15, lgrp = lane >> 4;
  const u16* Qz = Qb + (size_t)z * CS * CHD;
  const u16* Kz = Kb + (size_t)z * CS * CHD;
  const u16* Vz = Vt + (size_t)z * CHD * CS;

  for (int i = tid; i < CS; i += 256)
    bias[i] = amask[b * CS + i] ? 0.f : -1e30f;

  int qrow = qt * 64 + wid * 16 + lrow;
  short8 qf[4];
  #pragma unroll
  for (int kk = 0; kk < 4; ++kk)
    qf[kk] = *(const short8*)(Qz + (size_t)qrow * CHD + kk * 32 + lgrp * 8);

  float m_r[4], l_r[4];
  #pragma unroll
  for (int r = 0; r < 4; ++r) { m_r[r] = -3e38f; l_r[r] = 0.f; }
  f32x4 o_acc[8];
  #pragma unroll
  for (int dj = 0; dj < 8; ++dj) o_acc[dj] = (f32x4){0.f, 0.f, 0.f, 0.f};

  const float SCL = 0.08838834764831845f;

  for (int t = 0; t <= qt; ++t) {
    int k0 = t * 64;
    __syncthreads();
    #pragma unroll
    for (int it = 0; it < 4; ++it) {
      int c = it * 256 + tid;
      int key = c >> 4, ch = c & 15;
      short8 v = *(const short8*)(Kz + (size_t)(k0 + key) * CHD + ch * 8);
      *(short8*)((char*)Ks + key * 256 + ((ch * 16) ^ ((key & 7) << 4))) = v;
    }
    #pragma unroll
    for (int it = 0; it < 4; ++it) {
      int c = it * 256 + tid;
      int d = c >> 3, ch = c & 7;
      short8 v = *(const short8*)(Vz + (size_t)d * CS + k0 + ch * 8);
      *(short8*)((char*)Vs + d * 128 + ((ch * 16) ^ ((d & 7) << 4))) = v;
    }
    __syncthreads();

    f32x4 s_acc[4];
    #pragma unroll
    for (int nj = 0; nj < 4; ++nj) s_acc[nj] = (f32x4){0.f, 0.f, 0.f, 0.f};
    __builtin_amdgcn_s_setprio(1);
    #pragma unroll
    for (int kk = 0; kk < 4; ++kk) {
      #pragma unroll
      for (int nj = 0; nj < 4; ++nj) {
        int key = nj * 16 + lrow;
        short8 kf = *(const short8*)((const char*)Ks + key * 256 +
                                     (((kk * 32 + lgrp * 8) * 2) ^ ((key & 7) << 4)));
        s_acc[nj] = __builtin_amdgcn_mfma_f32_16x16x32_bf16(qf[kk], kf, s_acc[nj], 0, 0, 0);
      }
    }
    __builtin_amdgcn_s_setprio(0);

    bool diag = (t == qt);
    float p[4][4], mx[4];
    #pragma unroll
    for (int r = 0; r < 4; ++r) {
      int ql = wid * 16 + 4 * lgrp + r;
      float rm = -3e38f;
      #pragma unroll
      for (int nj = 0; nj < 4; ++nj) {
        int kl = nj * 16 + lrow;
        float v = s_acc[nj][r] * SCL + bias[k0 + kl];
        if (diag && kl > ql) v = -1e30f;
        p[nj][r] = v;
        rm = fmaxf(rm, v);
      }
      mx[r] = rm;
    }
    #pragma unroll
    for (int o = 1; o < 16; o <<= 1)
      #pragma unroll
      for (int r = 0; r < 4; ++r) mx[r] = fmaxf(mx[r], __shfl_xor(mx[r], o));
    float ps[4], alpha[4];
    #pragma unroll
    for (int r = 0; r < 4; ++r) {
      float mn = fmaxf(m_r[r], mx[r]);
      alpha[r] = __expf(m_r[r] - mn);
      m_r[r] = mn;
      float acc = 0.f;
      #pragma unroll
      for (int nj = 0; nj < 4; ++nj) {
        float e = __expf(p[nj][r] - mn);
        p[nj][r] = e;
        acc += e;
      }
      ps[r] = acc;
    }
    #pragma unroll
    for (int o = 1; o < 16; o <<= 1)
      #pragma unroll
      for (int r = 0; r < 4; ++r) ps[r] += __shfl_xor(ps[r], o);
    #pragma unroll
    for (int r = 0; r < 4; ++r) {
      l_r[r] = l_r[r] * alpha[r] + ps[r];
      #pragma unroll
      for (int dj = 0; dj < 8; ++dj) o_acc[dj][r] *= alpha[r];
    }

    #pragma unroll
    for (int r = 0; r < 4; ++r)
      #pragma unroll
      for (int nj = 0; nj < 4; ++nj)
        Ps[wid][4 * lgrp + r][nj * 16 + lrow] = f2bf(p[nj][r]);
    __builtin_amdgcn_s_setprio(1);
    #pragma unroll
    for (int kk2 = 0; kk2 < 2; ++kk2) {
      short8 pa = *(const short8*)(&Ps[wid][lrow][kk2 * 32 + lgrp * 8]);
      #pragma unroll
      for (int dj = 0; dj < 8; ++dj) {
        int d = dj * 16 + lrow;
        short8 vf = *(const short8*)((const char*)Vs + d * 128 +
                                     (((kk2 * 32 + lgrp * 8) * 2) ^ ((d & 7) << 4)));
        o_acc[dj] = __builtin_amdgcn_mfma_f32_16x16x32_bf16(pa, vf, o_acc[dj], 0, 0, 0);
      }
    }
    __builtin_amdgcn_s_setprio(0);
  }

  #pragma unroll
  for (int r = 0; r < 4; ++r) {
    float inv = 1.0f / l_r[r];
    int qg = qt * 64 + wid * 16 + 4 * lgrp + r;
    size_t rowoff = ((size_t)(b * CS + qg)) * CH + h * CHD;
    #pragma unroll
    for (int dj = 0; dj < 8; ++dj)
      out[rowoff + dj * 16 + lrow] = f2bf(o_acc[dj][r] * inv);
  }
}

// ---------------- fused silu-gate + LoRA xA (bf16 u input)
__global__ void k_silu_xa(const u16* __restrict__ u, const float* __restrict__ A,
                          u16* __restrict__ g, float* __restrict__ xA) {
  int m = blockIdx.x, tid = threadIdx.x;
  const u16* urow = u + (size_t)m * (2 * CFF);
  u16* grow = g + (size_t)m * CFF;
  float s0 = 0.f, s1 = 0.f;
  for (int c = tid; c < CFF / 8; c += 256) {
    short8 va = *(const short8*)(urow + c * 8);
    short8 vb = *(const short8*)(urow + CFF + c * 8);
    short8 og;
    #pragma unroll
    for (int e = 0; e < 8; ++e) {
      float a = bf2f((u16)va[e]);
      float bb = bf2f((u16)vb[e]);
      float gg = (a / (1.0f + __expf(-a))) * bb;
      og[e] = (short)f2bf(gg);
      s0 += gg * A[c * 8 + e];
      s1 += gg * A[CFF + c * 8 + e];
    }
    *(short8*)(grow + c * 8) = og;
  }
  s0 = blockReduceSum(s0);
  s1 = blockReduceSum(s1);
  if (tid == 0) { xA[2 * m] = s0; xA[2 * m + 1] = s1; }
}

// ---------------- k_gemm3: proven 2-buffer counted-vmcnt GEMM
template <int BM, int BN, int TW, int WM, int WN, int OUT_BF16, int LORA, int RESID>
__global__ __launch_bounds__(TW, 2) void k_gemm3(
    const u16* __restrict__ Ag, const u16* __restrict__ Bg, void* __restrict__ Cout,
    const float* __restrict__ resid, const float* __restrict__ xA,
    const float* __restrict__ lB, int K, int N) {
  constexpr int WROWS = BM / WM, WCOLS = BN / WN;
  constexpr int M_REP = WROWS / 16, N_REP = WCOLS / 16;
  constexpr int LA = BM * 8 / TW, LBN = BN * 8 / TW;
  constexpr int LPT = LA + LBN;
  __shared__ __align__(16) u16 As[2][BM * 64];
  __shared__ __align__(16) u16 Bs[2][BN * 64];
  int tid = threadIdx.x, lane = tid & 63, wid = tid >> 6;
  int wm = wid / WN, wn = wid % WN;
  int gx = gridDim.x, nwg = gx * gridDim.y;
  int bid = blockIdx.y * gx + blockIdx.x;
  int qq = nwg >> 3, rr = nwg & 7;
  int xcd = bid & 7, lid = bid >> 3;
  int swz = (xcd < rr ? xcd * (qq + 1) : rr * (qq + 1) + (xcd - rr) * qq) + lid;
  long bm = (long)(swz % gx) * BM, bn = (long)(swz / gx) * BN;

  f32x4 acc[M_REP][N_REP];
  #pragma unroll
  for (int i = 0; i < M_REP; ++i)
    #pragma unroll
    for (int j = 0; j < N_REP; ++j) acc[i][j] = (f32x4){0.f, 0.f, 0.f, 0.f};

  auto stage = [&](int buf, int t) {
    int k0 = t * 64;
    #pragma unroll
    for (int i = 0; i < LA; ++i) {
      int f = i * TW + tid;
      int r = f >> 3, g = (f & 7) ^ (r & 7);
      __builtin_amdgcn_global_load_lds(
          (const __attribute__((address_space(1))) void*)(Ag + (size_t)(bm + r) * K + k0 + g * 8),
          (__attribute__((address_space(3))) void*)(&As[buf][f * 8]), 16, 0, 0);
    }
    #pragma unroll
    for (int i = 0; i < LBN; ++i) {
      int f = i * TW + tid;
      int r = f >> 3, g = (f & 7) ^ (r & 7);
      __builtin_amdgcn_global_load_lds(
          (const __attribute__((address_space(1))) void*)(Bg + (size_t)(bn + r) * K + k0 + g * 8),
          (__attribute__((address_space(3))) void*)(&Bs[buf][f * 8]), 16, 0, 0);
    }
  };

  int NT = K >> 6;
  stage(0, 0);
  stage(1, 1);

  int kg = lane >> 4, lr = lane & 15;
  for (int t = 0; t < NT; ++t) {
    int buf = t & 1;
    if (t + 1 < NT) wait_vm<LPT>();
    else            wait_vm<0>();
    __builtin_amdgcn_s_barrier();

    short8 af[2][M_REP], bfr[2][N_REP];
    #pragma unroll
    for (int kk = 0; kk < 2; ++kk) {
      int au = kk * 4 + kg;
      #pragma unroll
      for (int i = 0; i < M_REP; ++i) {
        int r = wm * WROWS + i * 16 + lr;
        af[kk][i] = *(const short8*)(&As[buf][r * 64 + ((au ^ (r & 7)) << 3)]);
      }
      #pragma unroll
      for (int j = 0; j < N_REP; ++j) {
        int r = wn * WCOLS + j * 16 + lr;
        bfr[kk][j] = *(const short8*)(&Bs[buf][r * 64 + ((au ^ (r & 7)) << 3)]);
      }
    }
    asm volatile("s_waitcnt lgkmcnt(0)" ::: "memory");
    __builtin_amdgcn_s_barrier();
    if (t + 2 < NT) stage(buf, t + 2);

    __builtin_amdgcn_s_setprio(1);
    #pragma unroll
    for (int kk = 0; kk < 2; ++kk)
      #pragma unroll
      for (int i = 0; i < M_REP; ++i)
        #pragma unroll
        for (int j = 0; j < N_REP; ++j)
          acc[i][j] = __builtin_amdgcn_mfma_f32_16x16x32_bf16(af[kk][i], bfr[kk][j], acc[i][j], 0, 0, 0);
    __builtin_amdgcn_s_setprio(0);
  }

  #pragma unroll
  for (int i = 0; i < M_REP; ++i) {
    #pragma unroll
    for (int r = 0; r < 4; ++r) {
      long m = bm + wm * WROWS + i * 16 + ((lane >> 4) << 2) + r;
      float xa0 = 0.f, xa1 = 0.f;
      if (LORA) { xa0 = xA[2 * m]; xa1 = xA[2 * m + 1]; }
      #pragma unroll
      for (int j = 0; j < N_REP; ++j) {
        long n = bn + wn * WCOLS + j * 16 + (lane & 15);
        float v = acc[i][j][r];
        if (LORA) v += SCALING * (xa0 * lB[2 * n] + xa1 * lB[2 * n + 1]);
        if (RESID) v += resid[m * N + n];
        if (OUT_BF16)
          ((u16*)Cout)[m * N + n] = f2bf(v);
        else
          ((float*)Cout)[m * N + n] = v;
      }
    }
  }
}

// ---------------- k_gemm8: 256x256 8-wave 8-phase counted-vmcnt GEMM (R6-fixed)
#define RD_A(d, mh)                                                              \
  { _Pragma("unroll") for (int kk = 0; kk < 2; ++kk) {                           \
      _Pragma("unroll") for (int ii = 0; ii < 4; ++ii) {                         \
        int ra = ((mh) * 4 + ii) * 16 + lr;                                      \
        int slot = (kk * 4 + kg) ^ (ra & 7);                                     \
        a_f[kk][ii] = *(const short8*)(&As[d][wm][ra * 64 + slot * 8]);          \
      } } }
#define RD_B(d, nh)                                                              \
  { _Pragma("unroll") for (int kk = 0; kk < 2; ++kk) {                           \
      _Pragma("unroll") for (int jj = 0; jj < 2; ++jj) {                         \
        int rb = (wn & 1) * 64 + ((nh) * 2 + jj) * 16 + lr;                      \
        int slot = (kk * 4 + kg) ^ (rb & 7);                                     \
        b_f[nh][kk][jj] = *(const short8*)(&Bs[d][wn >> 1][rb * 64 + slot * 8]); \
      } } }
#define MFMA_Q(mh, nh)                                                           \
  { __builtin_amdgcn_s_setprio(1);                                               \
    _Pragma("unroll") for (int kk = 0; kk < 2; ++kk) {                           \
      _Pragma("unroll") for (int ii = 0; ii < 4; ++ii) {                         \
        _Pragma("unroll") for (int jj = 0; jj < 2; ++jj) {                       \
          acc[(mh) * 4 + ii][(nh) * 2 + jj] =                                    \
              __builtin_amdgcn_mfma_f32_16x16x32_bf16(                           \
                  a_f[kk][ii], b_f[nh][kk][jj],                                  \
                  acc[(mh) * 4 + ii][(nh) * 2 + jj], 0, 0, 0);                   \
        } } }                                                                    \
    __builtin_amdgcn_s_setprio(0); }
#define LGKM0_SB                                                                 \
  asm volatile("s_waitcnt lgkmcnt(0)" ::: "memory");                             \
  __builtin_amdgcn_sched_barrier(0);
#define BAR __builtin_amdgcn_s_barrier();

__global__ __launch_bounds__(512, 2) void k_gemm8(
    const u16* __restrict__ Ag, const u16* __restrict__ Bg, u16* __restrict__ Cout,
    const float* __restrict__ xA, const float* __restrict__ lB, int K, int N) {
  __shared__ __align__(16) u16 As[2][2][128 * 64];
  __shared__ __align__(16) u16 Bs[2][2][128 * 64];
  int tid = threadIdx.x, lane = tid & 63, wid = tid >> 6;
  int wm = wid >> 2, wn = wid & 3;
  int kg = lane >> 4, lr = lane & 15;
  int gx = gridDim.x, nwg = gx * gridDim.y;
  int bid = blockIdx.y * gx + blockIdx.x;
  int qq = nwg >> 3, rr = nwg & 7;
  int xcd = bid & 7, lid = bid >> 3;
  int swz = (xcd < rr ? xcd * (qq + 1) : rr * (qq + 1) + (xcd - rr) * qq) + lid;
  long bm = (long)(swz % gx) * 256, bn = (long)(swz / gx) * 256;
  const int NKT = K >> 6;

  f32x4 acc[8][4];
  #pragma unroll
  for (int i = 0; i < 8; ++i)
    #pragma unroll
    for (int j = 0; j < 4; ++j) acc[i][j] = (f32x4){0.f, 0.f, 0.f, 0.f};
  short8 a_f[2][4], b_f[2][2][2];

  auto stA = [&](int t, int h) {
    int d = t & 1;
    int tt = t < NKT ? t : NKT - 1;
    int k0 = tt << 6;
    #pragma unroll
    for (int ld = 0; ld < 2; ++ld) {
      int f = ld * 512 + tid;
      int row = f >> 3, p = f & 7;
      int ss = p ^ (row & 7);
      __builtin_amdgcn_global_load_lds(
          (const __attribute__((address_space(1))) void*)(Ag + (size_t)(bm + h * 128 + row) * K + k0 + ss * 8),
          (__attribute__((address_space(3))) void*)(&As[d][h][f * 8]), 16, 0, 0);
    }
  };
  auto stB = [&](int t, int h) {
    int d = t & 1;
    int tt = t < NKT ? t : NKT - 1;
    int k0 = tt << 6;
    #pragma unroll
    for (int ld = 0; ld < 2; ++ld) {
      int f = ld * 512 + tid;
      int row = f >> 3, p = f & 7;
      int ss = p ^ (row & 7);
      __builtin_amdgcn_global_load_lds(
          (const __attribute__((address_space(1))) void*)(Bg + (size_t)(bn + h * 128 + row) * K + k0 + ss * 8),
          (__attribute__((address_space(3))) void*)(&Bs[d][h][f * 8]), 16, 0, 0);
    }
  };

  stA(0, 0); stA(0, 1); stB(0, 0); stB(0, 1);
  stB(1, 0); stA(1, 0);
  asm volatile("s_waitcnt vmcnt(4)" ::: "memory");
  BAR

  int NI = NKT >> 1;
  for (int j = 0; j < NI; ++j) {
    int t0 = 2 * j;
    RD_A(0, 0) RD_B(0, 0)
    stA(t0 + 1, 1);
    BAR LGKM0_SB MFMA_Q(0, 0) BAR
    RD_B(0, 1)
    stB(t0 + 1, 1);
    BAR LGKM0_SB MFMA_Q(0, 1) BAR
    RD_A(0, 1)
    stB(t0 + 2, 0);
    BAR LGKM0_SB MFMA_Q(1, 0) BAR
    stA(t0 + 2, 0);
    asm volatile("s_waitcnt vmcnt(4)" ::: "memory");
    BAR MFMA_Q(1, 1) BAR
    RD_A(1, 0) RD_B(1, 0)
    stA(t0 + 2, 1);
    BAR LGKM0_SB MFMA_Q(0, 0) BAR
    RD_B(1, 1)
    stB(t0 + 2, 1);
    BAR LGKM0_SB MFMA_Q(0, 1) BAR
    RD_A(1, 1)
    stB(t0 + 3, 0);
    BAR LGKM0_SB MFMA_Q(1, 0) BAR
    stA(t0 + 3, 0);
    asm volatile("s_waitcnt vmcnt(4)" ::: "memory");
    BAR MFMA_Q(1, 1) BAR
  }

  #pragma unroll
  for (int i = 0; i < 8; ++i) {
    #pragma unroll
    for (int r = 0; r < 4; ++r) {
      long m = bm + wm * 128 + i * 16 + ((lane >> 4) << 2) + r;
      float xa0 = xA[2 * m], xa1 = xA[2 * m + 1];
      #pragma unroll
      for (int j = 0; j < 4; ++j) {
        long n = bn + wn * 64 + j * 16 + (lane & 15);
        float v = acc[i][j][r] + SCALING * (xa0 * lB[2 * n] + xa1 * lB[2 * n + 1]);
        Cout[m * N + n] = f2bf(v);
      }
    }
  }
}

// ---------------- final: LN-f on eos rows, logits, loss
__global__ void k_final(const float* __restrict__ x, const int* __restrict__ amask,
                        const int* __restrict__ labels, const float* __restrict__ g,
                        const float* __restrict__ bb, const float* __restrict__ cw,
                        float* __restrict__ out) {
  __shared__ float xr[CH];
  __shared__ float lg[CB][CNL];
  int tid = threadIdx.x;
  for (int b = 0; b < CB; ++b) {
    float fc = 0.f;
    for (int k = tid; k < CS; k += 256) fc += (amask[b * CS + k] != 0) ? 1.0f : 0.0f;
    int len = (int)(blockReduceSum(fc) + 0.5f);
    const float* row = x + ((size_t)b * CS + (len - 1)) * CH;
    float s = 0.f, s2 = 0.f;
    for (int k = tid; k < CH; k += 256) { float v = row[k]; s += v; s2 += v * v; }
    s = blockReduceSum(s);
    s2 = blockReduceSum(s2);
    float mu = s / CH, var = s2 / CH - mu * mu;
    float rs = rsqrtf(var + 1e-5f);
    for (int k = tid; k < CH; k += 256) xr[k] = (row[k] - mu) * rs * g[k] + bb[k];
    __syncthreads();
    for (int c = 0; c < CNL; ++c) {
      float p = 0.f;
      for (int k = tid; k < CH; k += 256) p += xr[k] * cw[c * CH + k];
      p = blockReduceSum(p);
      if (tid == 0) { lg[b][c] = p; out[1 + b * CNL + c] = p; }
    }
    __syncthreads();
  }
  if (tid == 0) {
    float loss = 0.f;
    for (int b = 0; b < CB; ++b) {
      float mx = -1e30f;
      for (int c = 0; c < CNL; ++c) mx = fmaxf(mx, lg[b][c]);
      float se = 0.f;
      for (int c = 0; c < CNL; ++c) se += expf(lg[b][c] - mx);
      float lse = mx + logf(se);
      loss -= (lg[b][labels[b]] - lse);
    }
    out[0] = loss / CB;
  }
}

// ---------------- workspace layout (bytes)
static constexpr size_t X_OFF  = 0;                                   // x f32
static constexpr size_t H_OFF  = X_OFF + (size_t)CM * CH * 4;         // hbuf bf16
static constexpr size_t W_OFF  = H_OFF + (size_t)CM * CH * 2;         // wbuf bf16 | Qb/Kb/Vt
static constexpr size_t SC_OFF = W_OFF + (size_t)8192 * 2048 * 2;     // qkv_out/ubuf bf16
static constexpr size_t PR_OFF = SC_OFF + (size_t)32 * CS * CS * 4;   // gbuf bf16
static constexpr size_t XA_OFF = PR_OFF + (size_t)32 * CS * CS * 2;   // xA f32
static constexpr size_t CS_OFF = XA_OFF + (size_t)CM * 2 * 4;
static constexpr size_t SN_OFF = CS_OFF + (size_t)CS * 64 * 4;
static constexpr size_t WS_END = SN_OFF + (size_t)CS * 64 * 4;

extern "C" void kernel_launch(void* const* d_in, const int* in_sizes, int n_in,
                              void* d_out, int out_size, void* d_ws, size_t ws_size,
                              hipStream_t stream) {
  (void)in_sizes; (void)n_in; (void)out_size;
  if (ws_size < WS_END) return;

  const int*   ids          = (const int*)d_in[0];
  const int*   amask        = (const int*)d_in[1];
  const int*   labels       = (const int*)d_in[2];
  const float* emb          = (const float*)d_in[3];
  const int*   qkv_codes    = (const int*)d_in[4];
  const float* qkv_scales   = (const float*)d_in[5];
  const float* qkv_A        = (const float*)d_in[6];
  const float* qkv_B        = (const float*)d_in[7];
  const int*   dense_codes  = (const int*)d_in[8];
  const float* dense_scales = (const float*)d_in[9];
  const float* dense_A      = (const float*)d_in[10];
  const float* dense_B      = (const float*)d_in[11];
  const int*   min_codes    = (const int*)d_in[12];
  const float* min_scales   = (const float*)d_in[13];
  const float* min_A        = (const float*)d_in[14];
  const float* min_B        = (const float*)d_in[15];
  const int*   mout_codes   = (const int*)d_in[16];
  const float* mout_scales  = (const float*)d_in[17];
  const float* mout_A       = (const float*)d_in[18];
  const float* mout_B       = (const float*)d_in[19];
  const float* ln1_g        = (const float*)d_in[20];
  const float* ln1_b        = (const float*)d_in[21];
  const float* ln2_g        = (const float*)d_in[22];
  const float* ln2_b        = (const float*)d_in[23];
  const float* lnf_g        = (const float*)d_in[24];
  const float* lnf_b        = (const float*)d_in[25];
  const float* cw           = (const float*)d_in[26];

  char* ws = (char*)d_ws;
  float* x       = (float*)(ws + X_OFF);
  u16*   hbuf    = (u16*)(ws + H_OFF);
  u16*   wbuf    = (u16*)(ws + W_OFF);
  u16*   Qb      = (u16*)(ws + W_OFF);                      // aliases wbuf (time-disjoint)
  u16*   Kb      = (u16*)(ws + W_OFF + (size_t)32 * CS * CHD * 2);
  u16*   Vt      = (u16*)(ws + W_OFF + (size_t)64 * CS * CHD * 2);
  u16*   qkv_out = (u16*)(ws + SC_OFF);
  u16*   ubuf    = (u16*)(ws + SC_OFF);
  u16*   gbuf    = (u16*)(ws + PR_OFF);
  float* xA      = (float*)(ws + XA_OFF);
  float* cosT    = (float*)(ws + CS_OFF);
  float* sinT    = (float*)(ws + SN_OFF);

  k_ropetab<<<(CS * 64 + 255) / 256, 256, 0, stream>>>(cosT, sinT);
  k_embed<<<CM, 256, 0, stream>>>(ids, emb, x);

  for (int l = 0; l < CL; ++l) {
    // ---- attention block
    k_ln_xa<<<CM, 256, 0, stream>>>(x, ln1_g + l * CH, ln1_b + l * CH,
                                    qkv_A + (size_t)l * 2 * CH, hbuf, xA);
    long nq = (long)3 * CH * CH;
    k_dequant<<<(int)(nq / 8 / 256), 256, 0, stream>>>(
        qkv_codes + (size_t)l * nq, qkv_scales + (size_t)l * 3 * CH * (CH / 64),
        wbuf, 11, nq);
    k_gemm3<128, 128, 256, 2, 2, 1, 1, 0><<<dim3(CM / 128, (3 * CH) / 128), 256, 0, stream>>>(
        hbuf, wbuf, qkv_out, nullptr, xA, qkv_B + (size_t)l * 3 * CH * 2, CH, 3 * CH);
    k_rope<<<32 * CS, 128, 0, stream>>>(qkv_out, cosT, sinT, Qb, Kb);
    k_vtrans<<<dim3(CS / 32, CHD / 32, 32), dim3(32, 8), 0, stream>>>(qkv_out, Vt);
    k_flash<<<512, 256, 0, stream>>>(Qb, Kb, Vt, amask, hbuf);
    k_xa<<<CM, 256, 0, stream>>>(hbuf, dense_A + (size_t)l * 2 * CH, xA, CH);
    long nd = (long)CH * CH;
    k_dequant<<<(int)(nd / 8 / 256), 256, 0, stream>>>(
        dense_codes + (size_t)l * nd, dense_scales + (size_t)l * CH * (CH / 64),
        wbuf, 11, nd);
    k_gemm3<128, 64, 256, 2, 2, 0, 1, 1><<<dim3(CM / 128, CH / 64), 256, 0, stream>>>(
        hbuf, wbuf, x, x, xA, dense_B + (size_t)l * CH * 2, CH, CH);

    // ---- MLP block
    k_ln_xa<<<CM, 256, 0, stream>>>(x, ln2_g + l * CH, ln2_b + l * CH,
                                    min_A + (size_t)l * 2 * CH, hbuf, xA);
    long nm = (long)2 * CFF * CH;
    k_dequant<<<(int)(nm / 8 / 256), 256, 0, stream>>>(
        min_codes + (size_t)l * nm, min_scales + (size_t)l * 2 * CFF * (CH / 64),
        wbuf, 11, nm);
    k_gemm8<<<dim3(CM / 256, (2 * CFF) / 256), 512, 0, stream>>>(
        hbuf, wbuf, ubuf, xA, min_B + (size_t)l * 2 * CFF * 2, CH, 2 * CFF);
    k_silu_xa<<<CM, 256, 0, stream>>>(ubuf, mout_A + (size_t)l * 2 * CFF, gbuf, xA);
    long no = (long)CH * CFF;
    k_dequant<<<(int)(no / 8 / 256), 256, 0, stream>>>(
        mout_codes + (size_t)l * no, mout_scales + (size_t)l * CH * (CFF / 64),
        wbuf, 12, no);
    k_gemm3<128, 64, 256, 2, 2, 0, 1, 1><<<dim3(CM / 128, CH / 64), 256, 0, stream>>>(
        gbuf, wbuf, x, x, xA, mout_B + (size_t)l * CH * 2, CFF, CH);
  }

  k_final<<<1, 256, 0, stream>>>(x, amask, labels, lnf_g, lnf_b, cw, (float*)d_out);
}

// Round 10
// 733.798 us; speedup vs baseline: 1.0547x; 1.0547x over previous
//
#include <hip/hip_runtime.h>

typedef unsigned short u16;
typedef __attribute__((ext_vector_type(4))) float f32x4;
typedef __attribute__((ext_vector_type(8))) short short8;
typedef __attribute__((ext_vector_type(4))) short short4v;

constexpr int CL  = 2;
constexpr int CH  = 2048;
constexpr int CNH = 16;
constexpr int CHD = 128;
constexpr int CFF = 4096;
constexpr int CS  = 1024;
constexpr int CB  = 2;
constexpr int CNL = 4;
constexpr int CM  = CB * CS;   // 2048 rows (B*S)
#define SCALING 8.0f

__device__ __constant__ float NF4TAB[16] = {
    -1.0f, -0.6961928009986877f, -0.5250730514526367f, -0.39491748809814453f,
    -0.28444138169288635f, -0.18477343022823334f, -0.09105003625154495f, 0.0f,
    0.07958029955625534f, 0.16093020141124725f, 0.24611230194568634f,
    0.33791524171829224f, 0.44070982933044434f, 0.5626170039176941f,
    0.7229568362236023f, 1.0f};

__device__ __forceinline__ u16 f2bf(float f) {
  union { float f; unsigned u; } v; v.f = f;
  unsigned r = v.u + 0x7fffu + ((v.u >> 16) & 1u);
  return (u16)(r >> 16);
}
__device__ __forceinline__ float bf2f(u16 u) {
  union { unsigned u; float f; } v; v.u = ((unsigned)u) << 16;
  return v.f;
}

template <int N> __device__ __forceinline__ void wait_vm() {
  if constexpr (N == 0)      asm volatile("s_waitcnt vmcnt(0)" ::: "memory");
  else if constexpr (N == 6) asm volatile("s_waitcnt vmcnt(6)" ::: "memory");
  else if constexpr (N == 8) asm volatile("s_waitcnt vmcnt(8)" ::: "memory");
  else                       asm volatile("s_waitcnt vmcnt(0)" ::: "memory");
}

__device__ __forceinline__ float blockReduceSum(float v) {
  __shared__ float sh[4];
  #pragma unroll
  for (int o = 32; o > 0; o >>= 1) v += __shfl_down(v, o);
  __syncthreads();
  if ((threadIdx.x & 63) == 0) sh[threadIdx.x >> 6] = v;
  __syncthreads();
  return sh[0] + sh[1] + sh[2] + sh[3];
}

// ---------------- embed gather
__global__ void k_embed(const int* __restrict__ ids, const float* __restrict__ emb,
                        float* __restrict__ x) {
  int m = blockIdx.x;
  const float4* src = (const float4*)(emb + (size_t)ids[m] * CH);
  float4* dst = (float4*)(x + (size_t)m * CH);
  for (int i = threadIdx.x; i < CH / 4; i += 256) dst[i] = src[i];
}

// ---------------- fused layernorm -> bf16  +  LoRA xA (R=2)
__global__ void k_ln_xa(const float* __restrict__ x, const float* __restrict__ g,
                        const float* __restrict__ b, const float* __restrict__ A,
                        u16* __restrict__ o, float* __restrict__ xA) {
  int m = blockIdx.x, tid = threadIdx.x;
  const float* row = x + (size_t)m * CH;
  float s = 0.f, s2 = 0.f;
  for (int i = tid; i < CH / 4; i += 256) {
    float4 v = ((const float4*)row)[i];
    s += v.x + v.y + v.z + v.w;
    s2 += v.x * v.x + v.y * v.y + v.z * v.z + v.w * v.w;
  }
  s = blockReduceSum(s);
  s2 = blockReduceSum(s2);
  float mu = s / CH, var = s2 / CH - mu * mu;
  float rs = rsqrtf(var + 1e-5f);
  u16* orow = o + (size_t)m * CH;
  float s0 = 0.f, s1 = 0.f;
  for (int i = tid; i < CH / 4; i += 256) {
    float4 v = ((const float4*)row)[i];
    float4 gv = ((const float4*)g)[i];
    float4 bv = ((const float4*)b)[i];
    float4 a0 = ((const float4*)A)[i];
    float4 a1 = ((const float4*)(A + CH))[i];
    float h0 = (v.x - mu) * rs * gv.x + bv.x;
    float h1 = (v.y - mu) * rs * gv.y + bv.y;
    float h2 = (v.z - mu) * rs * gv.z + bv.z;
    float h3 = (v.w - mu) * rs * gv.w + bv.w;
    short4v ov = { (short)f2bf(h0), (short)f2bf(h1), (short)f2bf(h2), (short)f2bf(h3) };
    *(short4v*)(orow + i * 4) = ov;
    s0 += h0 * a0.x + h1 * a0.y + h2 * a0.z + h3 * a0.w;
    s1 += h0 * a1.x + h1 * a1.y + h2 * a1.z + h3 * a1.w;
  }
  s0 = blockReduceSum(s0);
  s1 = blockReduceSum(s1);
  if (tid == 0) { xA[2 * m] = s0; xA[2 * m + 1] = s1; }
}

// ---------------- LoRA xA only (bf16 input)
__global__ void k_xa(const u16* __restrict__ xb, const float* __restrict__ A,
                     float* __restrict__ xA, int K) {
  int m = blockIdx.x, tid = threadIdx.x;
  const u16* row = xb + (size_t)m * K;
  float s0 = 0.f, s1 = 0.f;
  for (int c = tid; c < K / 8; c += 256) {
    short8 v = *(const short8*)(row + c * 8);
    #pragma unroll
    for (int e = 0; e < 8; ++e) {
      float f = bf2f((u16)v[e]);
      s0 += f * A[c * 8 + e];
      s1 += f * A[K + c * 8 + e];
    }
  }
  s0 = blockReduceSum(s0);
  s1 = blockReduceSum(s1);
  if (tid == 0) { xA[2 * m] = s0; xA[2 * m + 1] = s1; }
}

// ---------------- NF4 dequant -> bf16 row-major (N x K)
__global__ void k_dequant(const int* __restrict__ codes, const float* __restrict__ scales,
                          u16* __restrict__ w, int kshift, long total) {
  __shared__ float lut[16];
  if (threadIdx.x < 16) lut[threadIdx.x] = NF4TAB[threadIdx.x];
  __syncthreads();
  long base = ((long)blockIdx.x * 256 + threadIdx.x) * 8;
  if (base >= total) return;
  long n = base >> kshift;
  int k = (int)(base & ((1L << kshift) - 1));
  float sc = scales[(size_t)n * (1 << (kshift - 6)) + (k >> 6)];
  const int* cp = codes + base;
  short8 o;
  #pragma unroll
  for (int i = 0; i < 8; ++i) o[i] = (short)f2bf(lut[cp[i] & 15] * sc);
  *(short8*)(w + base) = o;
}

// ---------------- rope tables
__global__ void k_ropetab(float* __restrict__ cosT, float* __restrict__ sinT) {
  int i = blockIdx.x * 256 + threadIdx.x;
  if (i >= CS * 64) return;
  int s = i >> 6, d = i & 63;
  float inv = powf(10000.0f, -(float)d / 64.0f);
  float a = (float)s * inv;
  cosT[i] = cosf(a);
  sinT[i] = sinf(a);
}

// ---------------- rope + extract q,k -> (B,NH,S,HD) bf16  (bf16 input)
__global__ void k_rope(const u16* __restrict__ qkv, const float* __restrict__ cosT,
                       const float* __restrict__ sinT, u16* __restrict__ Qb,
                       u16* __restrict__ Kb) {
  int bid = blockIdx.x;            // z*CS + s
  int s = bid & (CS - 1);
  int z = bid >> 10;               // b*NH + h
  int b = z >> 4, h = z & 15;
  int d = threadIdx.x;             // 0..127
  const u16* base = qkv + ((size_t)(b * CS + s)) * (3 * CH) + h * (3 * CHD);
  int dh = d & 63;
  float c = cosT[s * 64 + dh], sn = sinT[s * 64 + dh];
  float sgn = (d < 64) ? -1.0f : 1.0f;
  float q = bf2f(base[d]),       qp = bf2f(base[d ^ 64]);
  float k = bf2f(base[CHD + d]), kp = bf2f(base[CHD + (d ^ 64)]);
  size_t oi = ((size_t)z * CS + s) * CHD + d;
  Qb[oi] = f2bf(q * c + sgn * qp * sn);
  Kb[oi] = f2bf(k * c + sgn * kp * sn);
}

// ---------------- V transpose -> (B,NH,HD,S) bf16  (bf16 input)
__global__ void k_vtrans(const u16* __restrict__ qkv, u16* __restrict__ Vt) {
  __shared__ u16 tile[32][33];
  int z = blockIdx.z;
  int b = z >> 4, h = z & 15;
  int s0 = blockIdx.x * 32, d0 = blockIdx.y * 32;
  int tx = threadIdx.x, ty = threadIdx.y;  // 32 x 8
  #pragma unroll
  for (int i = 0; i < 32; i += 8)
    tile[ty + i][tx] =
        qkv[((size_t)(b * CS + s0 + ty + i)) * (3 * CH) + h * (3 * CHD) + 2 * CHD + d0 + tx];
  __syncthreads();
  #pragma unroll
  for (int i = 0; i < 32; i += 8)
    Vt[((size_t)z * CHD + d0 + ty + i) * CS + s0 + tx] = tile[tx][ty + i];
}

// ---------------- flash attention (champion: serial-staged, (256,2), no setprio)
__global__ __launch_bounds__(256, 2) void k_flash(
    const u16* __restrict__ Qb, const u16* __restrict__ Kb, const u16* __restrict__ Vt,
    const int* __restrict__ amask, u16* __restrict__ out) {
  __shared__ u16 Ks[64 * 128];
  __shared__ u16 Vs[128 * 64];
  __shared__ float bias[CS];
  __shared__ u16 Ps[4][16][80];
  int bid = blockIdx.x;
  int qt = 15 - (bid >> 5);
  int z = bid & 31;
  int b = z >> 4, h = z & 15;
  int tid = threadIdx.x, lane = tid & 63, wid = tid >> 6;
  int lrow = lane & 15, lgrp = lane >> 4;
  const u16* Qz = Qb + (size_t)z * CS * CHD;
  const u16* Kz = Kb + (size_t)z * CS * CHD;
  const u16* Vz = Vt + (size_t)z * CHD * CS;

  for (int i = tid; i < CS; i += 256)
    bias[i] = amask[b * CS + i] ? 0.f : -1e30f;

  int qrow = qt * 64 + wid * 16 + lrow;
  short8 qf[4];
  #pragma unroll
  for (int kk = 0; kk < 4; ++kk)
    qf[kk] = *(const short8*)(Qz + (size_t)qrow * CHD + kk * 32 + lgrp * 8);

  float m_r[4], l_r[4];
  #pragma unroll
  for (int r = 0; r < 4; ++r) { m_r[r] = -3e38f; l_r[r] = 0.f; }
  f32x4 o_acc[8];
  #pragma unroll
  for (int dj = 0; dj < 8; ++dj) o_acc[dj] = (f32x4){0.f, 0.f, 0.f, 0.f};

  const float SCL = 0.08838834764831845f;

  for (int t = 0; t <= qt; ++t) {
    int k0 = t * 64;
    __syncthreads();
    #pragma unroll
    for (int it = 0; it < 4; ++it) {
      int c = it * 256 + tid;
      int key = c >> 4, ch = c & 15;
      short8 v = *(const short8*)(Kz + (size_t)(k0 + key) * CHD + ch * 8);
      *(short8*)((char*)Ks + key * 256 + ((ch * 16) ^ ((key & 7) << 4))) = v;
    }
    #pragma unroll
    for (int it = 0; it < 4; ++it) {
      int c = it * 256 + tid;
      int d = c >> 3, ch = c & 7;
      short8 v = *(const short8*)(Vz + (size_t)d * CS + k0 + ch * 8);
      *(short8*)((char*)Vs + d * 128 + ((ch * 16) ^ ((d & 7) << 4))) = v;
    }
    __syncthreads();

    f32x4 s_acc[4];
    #pragma unroll
    for (int nj = 0; nj < 4; ++nj) s_acc[nj] = (f32x4){0.f, 0.f, 0.f, 0.f};
    #pragma unroll
    for (int kk = 0; kk < 4; ++kk) {
      #pragma unroll
      for (int nj = 0; nj < 4; ++nj) {
        int key = nj * 16 + lrow;
        short8 kf = *(const short8*)((const char*)Ks + key * 256 +
                                     (((kk * 32 + lgrp * 8) * 2) ^ ((key & 7) << 4)));
        s_acc[nj] = __builtin_amdgcn_mfma_f32_16x16x32_bf16(qf[kk], kf, s_acc[nj], 0, 0, 0);
      }
    }

    bool diag = (t == qt);
    float p[4][4], mx[4];
    #pragma unroll
    for (int r = 0; r < 4; ++r) {
      int ql = wid * 16 + 4 * lgrp + r;
      float rm = -3e38f;
      #pragma unroll
      for (int nj = 0; nj < 4; ++nj) {
        int kl = nj * 16 + lrow;
        float v = s_acc[nj][r] * SCL + bias[k0 + kl];
        if (diag && kl > ql) v = -1e30f;
        p[nj][r] = v;
        rm = fmaxf(rm, v);
      }
      mx[r] = rm;
    }
    #pragma unroll
    for (int o = 1; o < 16; o <<= 1)
      #pragma unroll
      for (int r = 0; r < 4; ++r) mx[r] = fmaxf(mx[r], __shfl_xor(mx[r], o));
    float ps[4], alpha[4];
    #pragma unroll
    for (int r = 0; r < 4; ++r) {
      float mn = fmaxf(m_r[r], mx[r]);
      alpha[r] = __expf(m_r[r] - mn);
      m_r[r] = mn;
      float acc = 0.f;
      #pragma unroll
      for (int nj = 0; nj < 4; ++nj) {
        float e = __expf(p[nj][r] - mn);
        p[nj][r] = e;
        acc += e;
      }
      ps[r] = acc;
    }
    #pragma unroll
    for (int o = 1; o < 16; o <<= 1)
      #pragma unroll
      for (int r = 0; r < 4; ++r) ps[r] += __shfl_xor(ps[r], o);
    #pragma unroll
    for (int r = 0; r < 4; ++r) {
      l_r[r] = l_r[r] * alpha[r] + ps[r];
      #pragma unroll
      for (int dj = 0; dj < 8; ++dj) o_acc[dj][r] *= alpha[r];
    }

    #pragma unroll
    for (int r = 0; r < 4; ++r)
      #pragma unroll
      for (int nj = 0; nj < 4; ++nj)
        Ps[wid][4 * lgrp + r][nj * 16 + lrow] = f2bf(p[nj][r]);
    #pragma unroll
    for (int kk2 = 0; kk2 < 2; ++kk2) {
      short8 pa = *(const short8*)(&Ps[wid][lrow][kk2 * 32 + lgrp * 8]);
      #pragma unroll
      for (int dj = 0; dj < 8; ++dj) {
        int d = dj * 16 + lrow;
        short8 vf = *(const short8*)((const char*)Vs + d * 128 +
                                     (((kk2 * 32 + lgrp * 8) * 2) ^ ((d & 7) << 4)));
        o_acc[dj] = __builtin_amdgcn_mfma_f32_16x16x32_bf16(pa, vf, o_acc[dj], 0, 0, 0);
      }
    }
  }

  #pragma unroll
  for (int r = 0; r < 4; ++r) {
    float inv = 1.0f / l_r[r];
    int qg = qt * 64 + wid * 16 + 4 * lgrp + r;
    size_t rowoff = ((size_t)(b * CS + qg)) * CH + h * CHD;
    #pragma unroll
    for (int dj = 0; dj < 8; ++dj)
      out[rowoff + dj * 16 + lrow] = f2bf(o_acc[dj][r] * inv);
  }
}

// ---------------- fused silu-gate + LoRA xA (bf16 u input)
__global__ void k_silu_xa(const u16* __restrict__ u, const float* __restrict__ A,
                          u16* __restrict__ g, float* __restrict__ xA) {
  int m = blockIdx.x, tid = threadIdx.x;
  const u16* urow = u + (size_t)m * (2 * CFF);
  u16* grow = g + (size_t)m * CFF;
  float s0 = 0.f, s1 = 0.f;
  for (int c = tid; c < CFF / 8; c += 256) {
    short8 va = *(const short8*)(urow + c * 8);
    short8 vb = *(const short8*)(urow + CFF + c * 8);
    short8 og;
    #pragma unroll
    for (int e = 0; e < 8; ++e) {
      float a = bf2f((u16)va[e]);
      float bb = bf2f((u16)vb[e]);
      float gg = (a / (1.0f + __expf(-a))) * bb;
      og[e] = (short)f2bf(gg);
      s0 += gg * A[c * 8 + e];
      s1 += gg * A[CFF + c * 8 + e];
    }
    *(short8*)(grow + c * 8) = og;
  }
  s0 = blockReduceSum(s0);
  s1 = blockReduceSum(s1);
  if (tid == 0) { xA[2 * m] = s0; xA[2 * m + 1] = s1; }
}

// ---------------- k_gemm3: 2-buffer counted-vmcnt GEMM (champion)
template <int BM, int BN, int TW, int WM, int WN, int OUT_BF16, int LORA, int RESID>
__global__ __launch_bounds__(TW, 2) void k_gemm3(
    const u16* __restrict__ Ag, const u16* __restrict__ Bg, void* __restrict__ Cout,
    const float* __restrict__ resid, const float* __restrict__ xA,
    const float* __restrict__ lB, int K, int N) {
  constexpr int WROWS = BM / WM, WCOLS = BN / WN;
  constexpr int M_REP = WROWS / 16, N_REP = WCOLS / 16;
  constexpr int LA = BM * 8 / TW, LBN = BN * 8 / TW;
  constexpr int LPT = LA + LBN;
  __shared__ __align__(16) u16 As[2][BM * 64];
  __shared__ __align__(16) u16 Bs[2][BN * 64];
  int tid = threadIdx.x, lane = tid & 63, wid = tid >> 6;
  int wm = wid / WN, wn = wid % WN;
  int gx = gridDim.x, nwg = gx * gridDim.y;
  int bid = blockIdx.y * gx + blockIdx.x;
  int qq = nwg >> 3, rr = nwg & 7;
  int xcd = bid & 7, lid = bid >> 3;
  int swz = (xcd < rr ? xcd * (qq + 1) : rr * (qq + 1) + (xcd - rr) * qq) + lid;
  long bm = (long)(swz % gx) * BM, bn = (long)(swz / gx) * BN;

  f32x4 acc[M_REP][N_REP];
  #pragma unroll
  for (int i = 0; i < M_REP; ++i)
    #pragma unroll
    for (int j = 0; j < N_REP; ++j) acc[i][j] = (f32x4){0.f, 0.f, 0.f, 0.f};

  auto stage = [&](int buf, int t) {
    int k0 = t * 64;
    #pragma unroll
    for (int i = 0; i < LA; ++i) {
      int f = i * TW + tid;
      int r = f >> 3, g = (f & 7) ^ (r & 7);
      __builtin_amdgcn_global_load_lds(
          (const __attribute__((address_space(1))) void*)(Ag + (size_t)(bm + r) * K + k0 + g * 8),
          (__attribute__((address_space(3))) void*)(&As[buf][f * 8]), 16, 0, 0);
    }
    #pragma unroll
    for (int i = 0; i < LBN; ++i) {
      int f = i * TW + tid;
      int r = f >> 3, g = (f & 7) ^ (r & 7);
      __builtin_amdgcn_global_load_lds(
          (const __attribute__((address_space(1))) void*)(Bg + (size_t)(bn + r) * K + k0 + g * 8),
          (__attribute__((address_space(3))) void*)(&Bs[buf][f * 8]), 16, 0, 0);
    }
  };

  int NT = K >> 6;
  stage(0, 0);
  stage(1, 1);

  int kg = lane >> 4, lr = lane & 15;
  for (int t = 0; t < NT; ++t) {
    int buf = t & 1;
    if (t + 1 < NT) wait_vm<LPT>();
    else            wait_vm<0>();
    __builtin_amdgcn_s_barrier();

    short8 af[2][M_REP], bfr[2][N_REP];
    #pragma unroll
    for (int kk = 0; kk < 2; ++kk) {
      int au = kk * 4 + kg;
      #pragma unroll
      for (int i = 0; i < M_REP; ++i) {
        int r = wm * WROWS + i * 16 + lr;
        af[kk][i] = *(const short8*)(&As[buf][r * 64 + ((au ^ (r & 7)) << 3)]);
      }
      #pragma unroll
      for (int j = 0; j < N_REP; ++j) {
        int r = wn * WCOLS + j * 16 + lr;
        bfr[kk][j] = *(const short8*)(&Bs[buf][r * 64 + ((au ^ (r & 7)) << 3)]);
      }
    }
    asm volatile("s_waitcnt lgkmcnt(0)" ::: "memory");
    __builtin_amdgcn_s_barrier();
    if (t + 2 < NT) stage(buf, t + 2);

    __builtin_amdgcn_s_setprio(1);
    #pragma unroll
    for (int kk = 0; kk < 2; ++kk)
      #pragma unroll
      for (int i = 0; i < M_REP; ++i)
        #pragma unroll
        for (int j = 0; j < N_REP; ++j)
          acc[i][j] = __builtin_amdgcn_mfma_f32_16x16x32_bf16(af[kk][i], bfr[kk][j], acc[i][j], 0, 0, 0);
    __builtin_amdgcn_s_setprio(0);
  }

  #pragma unroll
  for (int i = 0; i < M_REP; ++i) {
    #pragma unroll
    for (int r = 0; r < 4; ++r) {
      long m = bm + wm * WROWS + i * 16 + ((lane >> 4) << 2) + r;
      float xa0 = 0.f, xa1 = 0.f;
      if (LORA) { xa0 = xA[2 * m]; xa1 = xA[2 * m + 1]; }
      #pragma unroll
      for (int j = 0; j < N_REP; ++j) {
        long n = bn + wn * WCOLS + j * 16 + (lane & 15);
        float v = acc[i][j][r];
        if (LORA) v += SCALING * (xa0 * lB[2 * n] + xa1 * lB[2 * n + 1]);
        if (RESID) v += resid[m * N + n];
        if (OUT_BF16)
          ((u16*)Cout)[m * N + n] = f2bf(v);
        else
          ((float*)Cout)[m * N + n] = v;
      }
    }
  }
}

// ---------------- final: LN-f on eos rows, logits, loss
__global__ void k_final(const float* __restrict__ x, const int* __restrict__ amask,
                        const int* __restrict__ labels, const float* __restrict__ g,
                        const float* __restrict__ bb, const float* __restrict__ cw,
                        float* __restrict__ out) {
  __shared__ float xr[CH];
  __shared__ float lg[CB][CNL];
  int tid = threadIdx.x;
  for (int b = 0; b < CB; ++b) {
    float fc = 0.f;
    for (int k = tid; k < CS; k += 256) fc += (amask[b * CS + k] != 0) ? 1.0f : 0.0f;
    int len = (int)(blockReduceSum(fc) + 0.5f);
    const float* row = x + ((size_t)b * CS + (len - 1)) * CH;
    float s = 0.f, s2 = 0.f;
    for (int k = tid; k < CH; k += 256) { float v = row[k]; s += v; s2 += v * v; }
    s = blockReduceSum(s);
    s2 = blockReduceSum(s2);
    float mu = s / CH, var = s2 / CH - mu * mu;
    float rs = rsqrtf(var + 1e-5f);
    for (int k = tid; k < CH; k += 256) xr[k] = (row[k] - mu) * rs * g[k] + bb[k];
    __syncthreads();
    for (int c = 0; c < CNL; ++c) {
      float p = 0.f;
      for (int k = tid; k < CH; k += 256) p += xr[k] * cw[c * CH + k];
      p = blockReduceSum(p);
      if (tid == 0) { lg[b][c] = p; out[1 + b * CNL + c] = p; }
    }
    __syncthreads();
  }
  if (tid == 0) {
    float loss = 0.f;
    for (int b = 0; b < CB; ++b) {
      float mx = -1e30f;
      for (int c = 0; c < CNL; ++c) mx = fmaxf(mx, lg[b][c]);
      float se = 0.f;
      for (int c = 0; c < CNL; ++c) se += expf(lg[b][c] - mx);
      float lse = mx + logf(se);
      loss -= (lg[b][labels[b]] - lse);
    }
    out[0] = loss / CB;
  }
}

// ---------------- workspace layout (bytes)
static constexpr size_t X_OFF  = 0;                                   // x f32
static constexpr size_t H_OFF  = X_OFF + (size_t)CM * CH * 4;         // hbuf bf16
static constexpr size_t W_OFF  = H_OFF + (size_t)CM * CH * 2;         // wbuf bf16 | Qb/Kb/Vt
static constexpr size_t SC_OFF = W_OFF + (size_t)8192 * 2048 * 2;     // qkv_out/ubuf bf16
static constexpr size_t PR_OFF = SC_OFF + (size_t)32 * CS * CS * 4;   // gbuf bf16
static constexpr size_t XA_OFF = PR_OFF + (size_t)32 * CS * CS * 2;   // xA f32
static constexpr size_t CS_OFF = XA_OFF + (size_t)CM * 2 * 4;
static constexpr size_t SN_OFF = CS_OFF + (size_t)CS * 64 * 4;
static constexpr size_t WS_END = SN_OFF + (size_t)CS * 64 * 4;

extern "C" void kernel_launch(void* const* d_in, const int* in_sizes, int n_in,
                              void* d_out, int out_size, void* d_ws, size_t ws_size,
                              hipStream_t stream) {
  (void)in_sizes; (void)n_in; (void)out_size;
  if (ws_size < WS_END) return;

  const int*   ids          = (const int*)d_in[0];
  const int*   amask        = (const int*)d_in[1];
  const int*   labels       = (const int*)d_in[2];
  const float* emb          = (const float*)d_in[3];
  const int*   qkv_codes    = (const int*)d_in[4];
  const float* qkv_scales   = (const float*)d_in[5];
  const float* qkv_A        = (const float*)d_in[6];
  const float* qkv_B        = (const float*)d_in[7];
  const int*   dense_codes  = (const int*)d_in[8];
  const float* dense_scales = (const float*)d_in[9];
  const float* dense_A      = (const float*)d_in[10];
  const float* dense_B      = (const float*)d_in[11];
  const int*   min_codes    = (const int*)d_in[12];
  const float* min_scales   = (const float*)d_in[13];
  const float* min_A        = (const float*)d_in[14];
  const float* min_B        = (const float*)d_in[15];
  const int*   mout_codes   = (const int*)d_in[16];
  const float* mout_scales  = (const float*)d_in[17];
  const float* mout_A       = (const float*)d_in[18];
  const float* mout_B       = (const float*)d_in[19];
  const float* ln1_g        = (const float*)d_in[20];
  const float* ln1_b        = (const float*)d_in[21];
  const float* ln2_g        = (const float*)d_in[22];
  const float* ln2_b        = (const float*)d_in[23];
  const float* lnf_g        = (const float*)d_in[24];
  const float* lnf_b        = (const float*)d_in[25];
  const float* cw           = (const float*)d_in[26];

  char* ws = (char*)d_ws;
  float* x       = (float*)(ws + X_OFF);
  u16*   hbuf    = (u16*)(ws + H_OFF);
  u16*   wbuf    = (u16*)(ws + W_OFF);
  u16*   Qb      = (u16*)(ws + W_OFF);                      // aliases wbuf (time-disjoint)
  u16*   Kb      = (u16*)(ws + W_OFF + (size_t)32 * CS * CHD * 2);
  u16*   Vt      = (u16*)(ws + W_OFF + (size_t)64 * CS * CHD * 2);
  u16*   qkv_out = (u16*)(ws + SC_OFF);
  u16*   ubuf    = (u16*)(ws + SC_OFF);
  u16*   gbuf    = (u16*)(ws + PR_OFF);
  float* xA      = (float*)(ws + XA_OFF);
  float* cosT    = (float*)(ws + CS_OFF);
  float* sinT    = (float*)(ws + SN_OFF);

  k_ropetab<<<(CS * 64 + 255) / 256, 256, 0, stream>>>(cosT, sinT);
  k_embed<<<CM, 256, 0, stream>>>(ids, emb, x);

  for (int l = 0; l < CL; ++l) {
    // ---- attention block
    k_ln_xa<<<CM, 256, 0, stream>>>(x, ln1_g + l * CH, ln1_b + l * CH,
                                    qkv_A + (size_t)l * 2 * CH, hbuf, xA);
    long nq = (long)3 * CH * CH;
    k_dequant<<<(int)(nq / 8 / 256), 256, 0, stream>>>(
        qkv_codes + (size_t)l * nq, qkv_scales + (size_t)l * 3 * CH * (CH / 64),
        wbuf, 11, nq);
    k_gemm3<128, 128, 256, 2, 2, 1, 1, 0><<<dim3(CM / 128, (3 * CH) / 128), 256, 0, stream>>>(
        hbuf, wbuf, qkv_out, nullptr, xA, qkv_B + (size_t)l * 3 * CH * 2, CH, 3 * CH);
    k_rope<<<32 * CS, 128, 0, stream>>>(qkv_out, cosT, sinT, Qb, Kb);
    k_vtrans<<<dim3(CS / 32, CHD / 32, 32), dim3(32, 8), 0, stream>>>(qkv_out, Vt);
    k_flash<<<512, 256, 0, stream>>>(Qb, Kb, Vt, amask, hbuf);
    k_xa<<<CM, 256, 0, stream>>>(hbuf, dense_A + (size_t)l * 2 * CH, xA, CH);
    long nd = (long)CH * CH;
    k_dequant<<<(int)(nd / 8 / 256), 256, 0, stream>>>(
        dense_codes + (size_t)l * nd, dense_scales + (size_t)l * CH * (CH / 64),
        wbuf, 11, nd);
    k_gemm3<128, 64, 256, 2, 2, 0, 1, 1><<<dim3(CM / 128, CH / 64), 256, 0, stream>>>(
        hbuf, wbuf, x, x, xA, dense_B + (size_t)l * CH * 2, CH, CH);

    // ---- MLP block
    k_ln_xa<<<CM, 256, 0, stream>>>(x, ln2_g + l * CH, ln2_b + l * CH,
                                    min_A + (size_t)l * 2 * CH, hbuf, xA);
    long nm = (long)2 * CFF * CH;
    k_dequant<<<(int)(nm / 8 / 256), 256, 0, stream>>>(
        min_codes + (size_t)l * nm, min_scales + (size_t)l * 2 * CFF * (CH / 64),
        wbuf, 11, nm);
    k_gemm3<128, 128, 256, 2, 2, 1, 1, 0><<<dim3(CM / 128, (2 * CFF) / 128), 256, 0, stream>>>(
        hbuf, wbuf, ubuf, nullptr, xA, min_B + (size_t)l * 2 * CFF * 2, CH, 2 * CFF);
    k_silu_xa<<<CM, 256, 0, stream>>>(ubuf, mout_A + (size_t)l * 2 * CFF, gbuf, xA);
    long no = (long)CH * CFF;
    k_dequant<<<(int)(no / 8 / 256), 256, 0, stream>>>(
        mout_codes + (size_t)l * no, mout_scales + (size_t)l * CH * (CFF / 64),
        wbuf, 12, no);
    k_gemm3<128, 64, 256, 2, 2, 0, 1, 1><<<dim3(CM / 128, CH / 64), 256, 0, stream>>>(
        gbuf, wbuf, x, x, xA, mout_B + (size_t)l * CH * 2, CFF, CH);
  }

  k_final<<<1, 256, 0, stream>>>(x, amask, labels, lnf_g, lnf_b, cw, (float*)d_out);
}

// Round 11
// 712.967 us; speedup vs baseline: 1.0855x; 1.0292x over previous
//
#include <hip/hip_runtime.h>

typedef unsigned short u16;
typedef __attribute__((ext_vector_type(4))) float f32x4;
typedef __attribute__((ext_vector_type(8))) short short8;
typedef __attribute__((ext_vector_type(4))) short short4v;

constexpr int CL  = 2;
constexpr int CH  = 2048;
constexpr int CNH = 16;
constexpr int CHD = 128;
constexpr int CFF = 4096;
constexpr int CS  = 1024;
constexpr int CB  = 2;
constexpr int CNL = 4;
constexpr int CM  = CB * CS;   // 2048 rows (B*S)
#define SCALING 8.0f

__device__ __constant__ float NF4TAB[16] = {
    -1.0f, -0.6961928009986877f, -0.5250730514526367f, -0.39491748809814453f,
    -0.28444138169288635f, -0.18477343022823334f, -0.09105003625154495f, 0.0f,
    0.07958029955625534f, 0.16093020141124725f, 0.24611230194568634f,
    0.33791524171829224f, 0.44070982933044434f, 0.5626170039176941f,
    0.7229568362236023f, 1.0f};

__device__ __forceinline__ u16 f2bf(float f) {
  union { float f; unsigned u; } v; v.f = f;
  unsigned r = v.u + 0x7fffu + ((v.u >> 16) & 1u);
  return (u16)(r >> 16);
}
__device__ __forceinline__ float bf2f(u16 u) {
  union { unsigned u; float f; } v; v.u = ((unsigned)u) << 16;
  return v.f;
}

template <int N> __device__ __forceinline__ void wait_vm() {
  if constexpr (N == 0)       asm volatile("s_waitcnt vmcnt(0)" ::: "memory");
  else if constexpr (N == 6)  asm volatile("s_waitcnt vmcnt(6)" ::: "memory");
  else if constexpr (N == 8)  asm volatile("s_waitcnt vmcnt(8)" ::: "memory");
  else if constexpr (N == 10) asm volatile("s_waitcnt vmcnt(10)" ::: "memory");
  else                        asm volatile("s_waitcnt vmcnt(0)" ::: "memory");
}

__device__ __forceinline__ float blockReduceSum(float v) {
  __shared__ float sh[4];
  #pragma unroll
  for (int o = 32; o > 0; o >>= 1) v += __shfl_down(v, o);
  __syncthreads();
  if ((threadIdx.x & 63) == 0) sh[threadIdx.x >> 6] = v;
  __syncthreads();
  return sh[0] + sh[1] + sh[2] + sh[3];
}

// ---------------- embed gather
__global__ void k_embed(const int* __restrict__ ids, const float* __restrict__ emb,
                        float* __restrict__ x) {
  int m = blockIdx.x;
  const float4* src = (const float4*)(emb + (size_t)ids[m] * CH);
  float4* dst = (float4*)(x + (size_t)m * CH);
  for (int i = threadIdx.x; i < CH / 4; i += 256) dst[i] = src[i];
}

// ---------------- fused layernorm -> bf16  +  LoRA xA (R=2)
__global__ void k_ln_xa(const float* __restrict__ x, const float* __restrict__ g,
                        const float* __restrict__ b, const float* __restrict__ A,
                        u16* __restrict__ o, float* __restrict__ xA) {
  int m = blockIdx.x, tid = threadIdx.x;
  const float* row = x + (size_t)m * CH;
  float s = 0.f, s2 = 0.f;
  for (int i = tid; i < CH / 4; i += 256) {
    float4 v = ((const float4*)row)[i];
    s += v.x + v.y + v.z + v.w;
    s2 += v.x * v.x + v.y * v.y + v.z * v.z + v.w * v.w;
  }
  s = blockReduceSum(s);
  s2 = blockReduceSum(s2);
  float mu = s / CH, var = s2 / CH - mu * mu;
  float rs = rsqrtf(var + 1e-5f);
  u16* orow = o + (size_t)m * CH;
  float s0 = 0.f, s1 = 0.f;
  for (int i = tid; i < CH / 4; i += 256) {
    float4 v = ((const float4*)row)[i];
    float4 gv = ((const float4*)g)[i];
    float4 bv = ((const float4*)b)[i];
    float4 a0 = ((const float4*)A)[i];
    float4 a1 = ((const float4*)(A + CH))[i];
    float h0 = (v.x - mu) * rs * gv.x + bv.x;
    float h1 = (v.y - mu) * rs * gv.y + bv.y;
    float h2 = (v.z - mu) * rs * gv.z + bv.z;
    float h3 = (v.w - mu) * rs * gv.w + bv.w;
    short4v ov = { (short)f2bf(h0), (short)f2bf(h1), (short)f2bf(h2), (short)f2bf(h3) };
    *(short4v*)(orow + i * 4) = ov;
    s0 += h0 * a0.x + h1 * a0.y + h2 * a0.z + h3 * a0.w;
    s1 += h0 * a1.x + h1 * a1.y + h2 * a1.z + h3 * a1.w;
  }
  s0 = blockReduceSum(s0);
  s1 = blockReduceSum(s1);
  if (tid == 0) { xA[2 * m] = s0; xA[2 * m + 1] = s1; }
}

// ---------------- LoRA xA only (bf16 input)
__global__ void k_xa(const u16* __restrict__ xb, const float* __restrict__ A,
                     float* __restrict__ xA, int K) {
  int m = blockIdx.x, tid = threadIdx.x;
  const u16* row = xb + (size_t)m * K;
  float s0 = 0.f, s1 = 0.f;
  for (int c = tid; c < K / 8; c += 256) {
    short8 v = *(const short8*)(row + c * 8);
    #pragma unroll
    for (int e = 0; e < 8; ++e) {
      float f = bf2f((u16)v[e]);
      s0 += f * A[c * 8 + e];
      s1 += f * A[K + c * 8 + e];
    }
  }
  s0 = blockReduceSum(s0);
  s1 = blockReduceSum(s1);
  if (tid == 0) { xA[2 * m] = s0; xA[2 * m + 1] = s1; }
}

// ---------------- NF4 dequant -> bf16 row-major (N x K)
__global__ void k_dequant(const int* __restrict__ codes, const float* __restrict__ scales,
                          u16* __restrict__ w, int kshift, long total) {
  __shared__ float lut[16];
  if (threadIdx.x < 16) lut[threadIdx.x] = NF4TAB[threadIdx.x];
  __syncthreads();
  long base = ((long)blockIdx.x * 256 + threadIdx.x) * 8;
  if (base >= total) return;
  long n = base >> kshift;
  int k = (int)(base & ((1L << kshift) - 1));
  float sc = scales[(size_t)n * (1 << (kshift - 6)) + (k >> 6)];
  const int* cp = codes + base;
  short8 o;
  #pragma unroll
  for (int i = 0; i < 8; ++i) o[i] = (short)f2bf(lut[cp[i] & 15] * sc);
  *(short8*)(w + base) = o;
}

// ---------------- rope tables
__global__ void k_ropetab(float* __restrict__ cosT, float* __restrict__ sinT) {
  int i = blockIdx.x * 256 + threadIdx.x;
  if (i >= CS * 64) return;
  int s = i >> 6, d = i & 63;
  float inv = powf(10000.0f, -(float)d / 64.0f);
  float a = (float)s * inv;
  cosT[i] = cosf(a);
  sinT[i] = sinf(a);
}

// ---------------- rope + extract q,k -> (B,NH,S,HD) bf16  (bf16 input)
__global__ void k_rope(const u16* __restrict__ qkv, const float* __restrict__ cosT,
                       const float* __restrict__ sinT, u16* __restrict__ Qb,
                       u16* __restrict__ Kb) {
  int bid = blockIdx.x;            // z*CS + s
  int s = bid & (CS - 1);
  int z = bid >> 10;               // b*NH + h
  int b = z >> 4, h = z & 15;
  int d = threadIdx.x;             // 0..127
  const u16* base = qkv + ((size_t)(b * CS + s)) * (3 * CH) + h * (3 * CHD);
  int dh = d & 63;
  float c = cosT[s * 64 + dh], sn = sinT[s * 64 + dh];
  float sgn = (d < 64) ? -1.0f : 1.0f;
  float q = bf2f(base[d]),       qp = bf2f(base[d ^ 64]);
  float k = bf2f(base[CHD + d]), kp = bf2f(base[CHD + (d ^ 64)]);
  size_t oi = ((size_t)z * CS + s) * CHD + d;
  Qb[oi] = f2bf(q * c + sgn * qp * sn);
  Kb[oi] = f2bf(k * c + sgn * kp * sn);
}

// ---------------- V transpose -> (B,NH,HD,S) bf16  (bf16 input)
__global__ void k_vtrans(const u16* __restrict__ qkv, u16* __restrict__ Vt) {
  __shared__ u16 tile[32][33];
  int z = blockIdx.z;
  int b = z >> 4, h = z & 15;
  int s0 = blockIdx.x * 32, d0 = blockIdx.y * 32;
  int tx = threadIdx.x, ty = threadIdx.y;  // 32 x 8
  #pragma unroll
  for (int i = 0; i < 32; i += 8)
    tile[ty + i][tx] =
        qkv[((size_t)(b * CS + s0 + ty + i)) * (3 * CH) + h * (3 * CHD) + 2 * CHD + d0 + tx];
  __syncthreads();
  #pragma unroll
  for (int i = 0; i < 32; i += 8)
    Vt[((size_t)z * CHD + d0 + ty + i) * CS + s0 + tx] = tile[tx][ty + i];
}

// ---------------- flash attention (champion: serial-staged, (256,2), no setprio)
__global__ __launch_bounds__(256, 2) void k_flash(
    const u16* __restrict__ Qb, const u16* __restrict__ Kb, const u16* __restrict__ Vt,
    const int* __restrict__ amask, u16* __restrict__ out) {
  __shared__ u16 Ks[64 * 128];
  __shared__ u16 Vs[128 * 64];
  __shared__ float bias[CS];
  __shared__ u16 Ps[4][16][80];
  int bid = blockIdx.x;
  int qt = 15 - (bid >> 5);
  int z = bid & 31;
  int b = z >> 4, h = z & 15;
  int tid = threadIdx.x, lane = tid & 63, wid = tid >> 6;
  int lrow = lane & 15, lgrp = lane >> 4;
  const u16* Qz = Qb + (size_t)z * CS * CHD;
  const u16* Kz = Kb + (size_t)z * CS * CHD;
  const u16* Vz = Vt + (size_t)z * CHD * CS;

  for (int i = tid; i < CS; i += 256)
    bias[i] = amask[b * CS + i] ? 0.f : -1e30f;

  int qrow = qt * 64 + wid * 16 + lrow;
  short8 qf[4];
  #pragma unroll
  for (int kk = 0; kk < 4; ++kk)
    qf[kk] = *(const short8*)(Qz + (size_t)qrow * CHD + kk * 32 + lgrp * 8);

  float m_r[4], l_r[4];
  #pragma unroll
  for (int r = 0; r < 4; ++r) { m_r[r] = -3e38f; l_r[r] = 0.f; }
  f32x4 o_acc[8];
  #pragma unroll
  for (int dj = 0; dj < 8; ++dj) o_acc[dj] = (f32x4){0.f, 0.f, 0.f, 0.f};

  const float SCL = 0.08838834764831845f;

  for (int t = 0; t <= qt; ++t) {
    int k0 = t * 64;
    __syncthreads();
    #pragma unroll
    for (int it = 0; it < 4; ++it) {
      int c = it * 256 + tid;
      int key = c >> 4, ch = c & 15;
      short8 v = *(const short8*)(Kz + (size_t)(k0 + key) * CHD + ch * 8);
      *(short8*)((char*)Ks + key * 256 + ((ch * 16) ^ ((key & 7) << 4))) = v;
    }
    #pragma unroll
    for (int it = 0; it < 4; ++it) {
      int c = it * 256 + tid;
      int d = c >> 3, ch = c & 7;
      short8 v = *(const short8*)(Vz + (size_t)d * CS + k0 + ch * 8);
      *(short8*)((char*)Vs + d * 128 + ((ch * 16) ^ ((d & 7) << 4))) = v;
    }
    __syncthreads();

    f32x4 s_acc[4];
    #pragma unroll
    for (int nj = 0; nj < 4; ++nj) s_acc[nj] = (f32x4){0.f, 0.f, 0.f, 0.f};
    #pragma unroll
    for (int kk = 0; kk < 4; ++kk) {
      #pragma unroll
      for (int nj = 0; nj < 4; ++nj) {
        int key = nj * 16 + lrow;
        short8 kf = *(const short8*)((const char*)Ks + key * 256 +
                                     (((kk * 32 + lgrp * 8) * 2) ^ ((key & 7) << 4)));
        s_acc[nj] = __builtin_amdgcn_mfma_f32_16x16x32_bf16(qf[kk], kf, s_acc[nj], 0, 0, 0);
      }
    }

    bool diag = (t == qt);
    float p[4][4], mx[4];
    #pragma unroll
    for (int r = 0; r < 4; ++r) {
      int ql = wid * 16 + 4 * lgrp + r;
      float rm = -3e38f;
      #pragma unroll
      for (int nj = 0; nj < 4; ++nj) {
        int kl = nj * 16 + lrow;
        float v = s_acc[nj][r] * SCL + bias[k0 + kl];
        if (diag && kl > ql) v = -1e30f;
        p[nj][r] = v;
        rm = fmaxf(rm, v);
      }
      mx[r] = rm;
    }
    #pragma unroll
    for (int o = 1; o < 16; o <<= 1)
      #pragma unroll
      for (int r = 0; r < 4; ++r) mx[r] = fmaxf(mx[r], __shfl_xor(mx[r], o));
    float ps[4], alpha[4];
    #pragma unroll
    for (int r = 0; r < 4; ++r) {
      float mn = fmaxf(m_r[r], mx[r]);
      alpha[r] = __expf(m_r[r] - mn);
      m_r[r] = mn;
      float acc = 0.f;
      #pragma unroll
      for (int nj = 0; nj < 4; ++nj) {
        float e = __expf(p[nj][r] - mn);
        p[nj][r] = e;
        acc += e;
      }
      ps[r] = acc;
    }
    #pragma unroll
    for (int o = 1; o < 16; o <<= 1)
      #pragma unroll
      for (int r = 0; r < 4; ++r) ps[r] += __shfl_xor(ps[r], o);
    #pragma unroll
    for (int r = 0; r < 4; ++r) {
      l_r[r] = l_r[r] * alpha[r] + ps[r];
      #pragma unroll
      for (int dj = 0; dj < 8; ++dj) o_acc[dj][r] *= alpha[r];
    }

    #pragma unroll
    for (int r = 0; r < 4; ++r)
      #pragma unroll
      for (int nj = 0; nj < 4; ++nj)
        Ps[wid][4 * lgrp + r][nj * 16 + lrow] = f2bf(p[nj][r]);
    #pragma unroll
    for (int kk2 = 0; kk2 < 2; ++kk2) {
      short8 pa = *(const short8*)(&Ps[wid][lrow][kk2 * 32 + lgrp * 8]);
      #pragma unroll
      for (int dj = 0; dj < 8; ++dj) {
        int d = dj * 16 + lrow;
        short8 vf = *(const short8*)((const char*)Vs + d * 128 +
                                     (((kk2 * 32 + lgrp * 8) * 2) ^ ((d & 7) << 4)));
        o_acc[dj] = __builtin_amdgcn_mfma_f32_16x16x32_bf16(pa, vf, o_acc[dj], 0, 0, 0);
      }
    }
  }

  #pragma unroll
  for (int r = 0; r < 4; ++r) {
    float inv = 1.0f / l_r[r];
    int qg = qt * 64 + wid * 16 + 4 * lgrp + r;
    size_t rowoff = ((size_t)(b * CS + qg)) * CH + h * CHD;
    #pragma unroll
    for (int dj = 0; dj < 8; ++dj)
      out[rowoff + dj * 16 + lrow] = f2bf(o_acc[dj][r] * inv);
  }
}

// ---------------- fused silu-gate + LoRA xA (bf16 u input)
__global__ void k_silu_xa(const u16* __restrict__ u, const float* __restrict__ A,
                          u16* __restrict__ g, float* __restrict__ xA) {
  int m = blockIdx.x, tid = threadIdx.x;
  const u16* urow = u + (size_t)m * (2 * CFF);
  u16* grow = g + (size_t)m * CFF;
  float s0 = 0.f, s1 = 0.f;
  for (int c = tid; c < CFF / 8; c += 256) {
    short8 va = *(const short8*)(urow + c * 8);
    short8 vb = *(const short8*)(urow + CFF + c * 8);
    short8 og;
    #pragma unroll
    for (int e = 0; e < 8; ++e) {
      float a = bf2f((u16)va[e]);
      float bb = bf2f((u16)vb[e]);
      float gg = (a / (1.0f + __expf(-a))) * bb;
      og[e] = (short)f2bf(gg);
      s0 += gg * A[c * 8 + e];
      s1 += gg * A[CFF + c * 8 + e];
    }
    *(short8*)(grow + c * 8) = og;
  }
  s0 = blockReduceSum(s0);
  s1 = blockReduceSum(s1);
  if (tid == 0) { xA[2 * m] = s0; xA[2 * m + 1] = s1; }
}

// ---------------- k_gemm3: 2-buffer counted-vmcnt GEMM (champion)
template <int BM, int BN, int TW, int WM, int WN, int OUT_BF16, int LORA, int RESID>
__global__ __launch_bounds__(TW, 2) void k_gemm3(
    const u16* __restrict__ Ag, const u16* __restrict__ Bg, void* __restrict__ Cout,
    const float* __restrict__ resid, const float* __restrict__ xA,
    const float* __restrict__ lB, int K, int N) {
  constexpr int WROWS = BM / WM, WCOLS = BN / WN;
  constexpr int M_REP = WROWS / 16, N_REP = WCOLS / 16;
  constexpr int LA = BM * 8 / TW, LBN = BN * 8 / TW;
  constexpr int LPT = LA + LBN;
  __shared__ __align__(16) u16 As[2][BM * 64];
  __shared__ __align__(16) u16 Bs[2][BN * 64];
  int tid = threadIdx.x, lane = tid & 63, wid = tid >> 6;
  int wm = wid / WN, wn = wid % WN;
  int gx = gridDim.x, nwg = gx * gridDim.y;
  int bid = blockIdx.y * gx + blockIdx.x;
  int qq = nwg >> 3, rr = nwg & 7;
  int xcd = bid & 7, lid = bid >> 3;
  int swz = (xcd < rr ? xcd * (qq + 1) : rr * (qq + 1) + (xcd - rr) * qq) + lid;
  long bm = (long)(swz % gx) * BM, bn = (long)(swz / gx) * BN;

  f32x4 acc[M_REP][N_REP];
  #pragma unroll
  for (int i = 0; i < M_REP; ++i)
    #pragma unroll
    for (int j = 0; j < N_REP; ++j) acc[i][j] = (f32x4){0.f, 0.f, 0.f, 0.f};

  auto stage = [&](int buf, int t) {
    int k0 = t * 64;
    #pragma unroll
    for (int i = 0; i < LA; ++i) {
      int f = i * TW + tid;
      int r = f >> 3, g = (f & 7) ^ (r & 7);
      __builtin_amdgcn_global_load_lds(
          (const __attribute__((address_space(1))) void*)(Ag + (size_t)(bm + r) * K + k0 + g * 8),
          (__attribute__((address_space(3))) void*)(&As[buf][f * 8]), 16, 0, 0);
    }
    #pragma unroll
    for (int i = 0; i < LBN; ++i) {
      int f = i * TW + tid;
      int r = f >> 3, g = (f & 7) ^ (r & 7);
      __builtin_amdgcn_global_load_lds(
          (const __attribute__((address_space(1))) void*)(Bg + (size_t)(bn + r) * K + k0 + g * 8),
          (__attribute__((address_space(3))) void*)(&Bs[buf][f * 8]), 16, 0, 0);
    }
  };

  int NT = K >> 6;
  stage(0, 0);
  stage(1, 1);

  int kg = lane >> 4, lr = lane & 15;
  for (int t = 0; t < NT; ++t) {
    int buf = t & 1;
    if (t + 1 < NT) wait_vm<LPT>();
    else            wait_vm<0>();
    __builtin_amdgcn_s_barrier();

    short8 af[2][M_REP], bfr[2][N_REP];
    #pragma unroll
    for (int kk = 0; kk < 2; ++kk) {
      int au = kk * 4 + kg;
      #pragma unroll
      for (int i = 0; i < M_REP; ++i) {
        int r = wm * WROWS + i * 16 + lr;
        af[kk][i] = *(const short8*)(&As[buf][r * 64 + ((au ^ (r & 7)) << 3)]);
      }
      #pragma unroll
      for (int j = 0; j < N_REP; ++j) {
        int r = wn * WCOLS + j * 16 + lr;
        bfr[kk][j] = *(const short8*)(&Bs[buf][r * 64 + ((au ^ (r & 7)) << 3)]);
      }
    }
    asm volatile("s_waitcnt lgkmcnt(0)" ::: "memory");
    __builtin_amdgcn_s_barrier();
    if (t + 2 < NT) stage(buf, t + 2);

    __builtin_amdgcn_s_setprio(1);
    #pragma unroll
    for (int kk = 0; kk < 2; ++kk)
      #pragma unroll
      for (int i = 0; i < M_REP; ++i)
        #pragma unroll
        for (int j = 0; j < N_REP; ++j)
          acc[i][j] = __builtin_amdgcn_mfma_f32_16x16x32_bf16(af[kk][i], bfr[kk][j], acc[i][j], 0, 0, 0);
    __builtin_amdgcn_s_setprio(0);
  }

  #pragma unroll
  for (int i = 0; i < M_REP; ++i) {
    #pragma unroll
    for (int r = 0; r < 4; ++r) {
      long m = bm + wm * WROWS + i * 16 + ((lane >> 4) << 2) + r;
      float xa0 = 0.f, xa1 = 0.f;
      if (LORA) { xa0 = xA[2 * m]; xa1 = xA[2 * m + 1]; }
      #pragma unroll
      for (int j = 0; j < N_REP; ++j) {
        long n = bn + wn * WCOLS + j * 16 + (lane & 15);
        float v = acc[i][j][r];
        if (LORA) v += SCALING * (xa0 * lB[2 * n] + xa1 * lB[2 * n + 1]);
        if (RESID) v += resid[m * N + n];
        if (OUT_BF16)
          ((u16*)Cout)[m * N + n] = f2bf(v);
        else
          ((float*)Cout)[m * N + n] = v;
      }
    }
  }
}

// ---------------- final: LN-f on eos rows, logits, loss
__global__ void k_final(const float* __restrict__ x, const int* __restrict__ amask,
                        const int* __restrict__ labels, const float* __restrict__ g,
                        const float* __restrict__ bb, const float* __restrict__ cw,
                        float* __restrict__ out) {
  __shared__ float xr[CH];
  __shared__ float lg[CB][CNL];
  int tid = threadIdx.x;
  for (int b = 0; b < CB; ++b) {
    float fc = 0.f;
    for (int k = tid; k < CS; k += 256) fc += (amask[b * CS + k] != 0) ? 1.0f : 0.0f;
    int len = (int)(blockReduceSum(fc) + 0.5f);
    const float* row = x + ((size_t)b * CS + (len - 1)) * CH;
    float s = 0.f, s2 = 0.f;
    for (int k = tid; k < CH; k += 256) { float v = row[k]; s += v; s2 += v * v; }
    s = blockReduceSum(s);
    s2 = blockReduceSum(s2);
    float mu = s / CH, var = s2 / CH - mu * mu;
    float rs = rsqrtf(var + 1e-5f);
    for (int k = tid; k < CH; k += 256) xr[k] = (row[k] - mu) * rs * g[k] + bb[k];
    __syncthreads();
    for (int c = 0; c < CNL; ++c) {
      float p = 0.f;
      for (int k = tid; k < CH; k += 256) p += xr[k] * cw[c * CH + k];
      p = blockReduceSum(p);
      if (tid == 0) { lg[b][c] = p; out[1 + b * CNL + c] = p; }
    }
    __syncthreads();
  }
  if (tid == 0) {
    float loss = 0.f;
    for (int b = 0; b < CB; ++b) {
      float mx = -1e30f;
      for (int c = 0; c < CNL; ++c) mx = fmaxf(mx, lg[b][c]);
      float se = 0.f;
      for (int c = 0; c < CNL; ++c) se += expf(lg[b][c] - mx);
      float lse = mx + logf(se);
      loss -= (lg[b][labels[b]] - lse);
    }
    out[0] = loss / CB;
  }
}

// ---------------- workspace layout (bytes)
static constexpr size_t X_OFF  = 0;                                   // x f32
static constexpr size_t H_OFF  = X_OFF + (size_t)CM * CH * 4;         // hbuf bf16
static constexpr size_t W_OFF  = H_OFF + (size_t)CM * CH * 2;         // wbuf bf16 | Qb/Kb/Vt
static constexpr size_t SC_OFF = W_OFF + (size_t)8192 * 2048 * 2;     // qkv_out/ubuf bf16
static constexpr size_t PR_OFF = SC_OFF + (size_t)32 * CS * CS * 4;   // gbuf bf16
static constexpr size_t XA_OFF = PR_OFF + (size_t)32 * CS * CS * 2;   // xA f32
static constexpr size_t CS_OFF = XA_OFF + (size_t)CM * 2 * 4;
static constexpr size_t SN_OFF = CS_OFF + (size_t)CS * 64 * 4;
static constexpr size_t WS_END = SN_OFF + (size_t)CS * 64 * 4;

extern "C" void kernel_launch(void* const* d_in, const int* in_sizes, int n_in,
                              void* d_out, int out_size, void* d_ws, size_t ws_size,
                              hipStream_t stream) {
  (void)in_sizes; (void)n_in; (void)out_size;
  if (ws_size < WS_END) return;

  const int*   ids          = (const int*)d_in[0];
  const int*   amask        = (const int*)d_in[1];
  const int*   labels       = (const int*)d_in[2];
  const float* emb          = (const float*)d_in[3];
  const int*   qkv_codes    = (const int*)d_in[4];
  const float* qkv_scales   = (const float*)d_in[5];
  const float* qkv_A        = (const float*)d_in[6];
  const float* qkv_B        = (const float*)d_in[7];
  const int*   dense_codes  = (const int*)d_in[8];
  const float* dense_scales = (const float*)d_in[9];
  const float* dense_A      = (const float*)d_in[10];
  const float* dense_B      = (const float*)d_in[11];
  const int*   min_codes    = (const int*)d_in[12];
  const float* min_scales   = (const float*)d_in[13];
  const float* min_A        = (const float*)d_in[14];
  const float* min_B        = (const float*)d_in[15];
  const int*   mout_codes   = (const int*)d_in[16];
  const float* mout_scales  = (const float*)d_in[17];
  const float* mout_A       = (const float*)d_in[18];
  const float* mout_B       = (const float*)d_in[19];
  const float* ln1_g        = (const float*)d_in[20];
  const float* ln1_b        = (const float*)d_in[21];
  const float* ln2_g        = (const float*)d_in[22];
  const float* ln2_b        = (const float*)d_in[23];
  const float* lnf_g        = (const float*)d_in[24];
  const float* lnf_b        = (const float*)d_in[25];
  const float* cw           = (const float*)d_in[26];

  char* ws = (char*)d_ws;
  float* x       = (float*)(ws + X_OFF);
  u16*   hbuf    = (u16*)(ws + H_OFF);
  u16*   wbuf    = (u16*)(ws + W_OFF);
  u16*   Qb      = (u16*)(ws + W_OFF);                      // aliases wbuf (time-disjoint)
  u16*   Kb      = (u16*)(ws + W_OFF + (size_t)32 * CS * CHD * 2);
  u16*   Vt      = (u16*)(ws + W_OFF + (size_t)64 * CS * CHD * 2);
  u16*   qkv_out = (u16*)(ws + SC_OFF);
  u16*   ubuf    = (u16*)(ws + SC_OFF);
  u16*   gbuf    = (u16*)(ws + PR_OFF);
  float* xA      = (float*)(ws + XA_OFF);
  float* cosT    = (float*)(ws + CS_OFF);
  float* sinT    = (float*)(ws + SN_OFF);

  k_ropetab<<<(CS * 64 + 255) / 256, 256, 0, stream>>>(cosT, sinT);
  k_embed<<<CM, 256, 0, stream>>>(ids, emb, x);

  for (int l = 0; l < CL; ++l) {
    // ---- attention block
    k_ln_xa<<<CM, 256, 0, stream>>>(x, ln1_g + l * CH, ln1_b + l * CH,
                                    qkv_A + (size_t)l * 2 * CH, hbuf, xA);
    long nq = (long)3 * CH * CH;
    k_dequant<<<(int)(nq / 8 / 256), 256, 0, stream>>>(
        qkv_codes + (size_t)l * nq, qkv_scales + (size_t)l * 3 * CH * (CH / 64),
        wbuf, 11, nq);
    // BN=192: grid 16x32 = 512 blocks = exactly 2/CU, one full pass (was 768 = 1.5 passes)
    k_gemm3<128, 192, 256, 2, 2, 1, 1, 0><<<dim3(CM / 128, (3 * CH) / 192), 256, 0, stream>>>(
        hbuf, wbuf, qkv_out, nullptr, xA, qkv_B + (size_t)l * 3 * CH * 2, CH, 3 * CH);
    k_rope<<<32 * CS, 128, 0, stream>>>(qkv_out, cosT, sinT, Qb, Kb);
    k_vtrans<<<dim3(CS / 32, CHD / 32, 32), dim3(32, 8), 0, stream>>>(qkv_out, Vt);
    k_flash<<<512, 256, 0, stream>>>(Qb, Kb, Vt, amask, hbuf);
    k_xa<<<CM, 256, 0, stream>>>(hbuf, dense_A + (size_t)l * 2 * CH, xA, CH);
    long nd = (long)CH * CH;
    k_dequant<<<(int)(nd / 8 / 256), 256, 0, stream>>>(
        dense_codes + (size_t)l * nd, dense_scales + (size_t)l * CH * (CH / 64),
        wbuf, 11, nd);
    k_gemm3<128, 64, 256, 2, 2, 0, 1, 1><<<dim3(CM / 128, CH / 64), 256, 0, stream>>>(
        hbuf, wbuf, x, x, xA, dense_B + (size_t)l * CH * 2, CH, CH);

    // ---- MLP block
    k_ln_xa<<<CM, 256, 0, stream>>>(x, ln2_g + l * CH, ln2_b + l * CH,
                                    min_A + (size_t)l * 2 * CH, hbuf, xA);
    long nm = (long)2 * CFF * CH;
    k_dequant<<<(int)(nm / 8 / 256), 256, 0, stream>>>(
        min_codes + (size_t)l * nm, min_scales + (size_t)l * 2 * CFF * (CH / 64),
        wbuf, 11, nm);
    k_gemm3<128, 128, 256, 2, 2, 1, 1, 0><<<dim3(CM / 128, (2 * CFF) / 128), 256, 0, stream>>>(
        hbuf, wbuf, ubuf, nullptr, xA, min_B + (size_t)l * 2 * CFF * 2, CH, 2 * CFF);
    k_silu_xa<<<CM, 256, 0, stream>>>(ubuf, mout_A + (size_t)l * 2 * CFF, gbuf, xA);
    long no = (long)CH * CFF;
    k_dequant<<<(int)(no / 8 / 256), 256, 0, stream>>>(
        mout_codes + (size_t)l * no, mout_scales + (size_t)l * CH * (CFF / 64),
        wbuf, 12, no);
    k_gemm3<128, 64, 256, 2, 2, 0, 1, 1><<<dim3(CM / 128, CH / 64), 256, 0, stream>>>(
        gbuf, wbuf, x, x, xA, mout_B + (size_t)l * CH * 2, CFF, CH);
  }

  k_final<<<1, 256, 0, stream>>>(x, amask, labels, lnf_g, lnf_b, cw, (float*)d_out);
}